// Round 9
// baseline (340.793 us; speedup 1.0000x reference)
//
#include <hip/hip_runtime.h>
#include <hip/hip_bf16.h>

static constexpr int KD  = 64;
static constexpr int KH  = 64;

typedef __attribute__((ext_vector_type(8))) short bf16x8;
typedef __attribute__((ext_vector_type(4))) float f32x4;
typedef __attribute__((ext_vector_type(2))) float f32x2;

__device__ inline unsigned short f2bf(float f) {
  union { float f; unsigned u; } uf; uf.f = f;
  unsigned u = uf.u;
  return (unsigned short)((u + 0x7FFFu + ((u >> 16) & 1u)) >> 16);
}
__device__ inline float bf2f(unsigned short h) {
  union { unsigned u; float f; } x; x.u = ((unsigned)h) << 16; return x.f;
}
__device__ inline bf16x8 pack8(const float* p) {
  float4 lo = *(const float4*)p;
  float4 hi = *(const float4*)(p + 4);
  bf16x8 v;
  v[0] = (short)f2bf(lo.x); v[1] = (short)f2bf(lo.y);
  v[2] = (short)f2bf(lo.z); v[3] = (short)f2bf(lo.w);
  v[4] = (short)f2bf(hi.x); v[5] = (short)f2bf(hi.y);
  v[6] = (short)f2bf(hi.z); v[7] = (short)f2bf(hi.w);
  return v;
}
__device__ inline float sigm(float x) { return 1.0f / (1.0f + __expf(-x)); }
__device__ inline float silu_(float x) { return x * sigm(x); }
__device__ inline unsigned pk_fp8x4(float a0, float a1, float a2, float a3) {
  int v = __builtin_amdgcn_cvt_pk_fp8_f32(a0, a1, 0, false);
  v = __builtin_amdgcn_cvt_pk_fp8_f32(a2, a3, v, true);
  return (unsigned)v;
}
// HW packed bf16 convert: 1 inst for 2 values
__device__ inline unsigned cvtpk_bf16(float lo, float hi) {
  unsigned r;
  asm("v_cvt_pk_bf16_f32 %0, %1, %2" : "=v"(r) : "v"(lo), "v"(hi));
  return r;
}
// sum of one fp8 pair-slot across 4 source words (f32x2 adds -> v_pk_add_f32).
// HI is a template param: the builtin's word-select must be a compile-time constant.
template<bool HI>
__device__ inline f32x2 sumpair_fp8(unsigned a, unsigned b, unsigned c, unsigned d) {
  f32x2 A = __builtin_amdgcn_cvt_pk_f32_fp8((int)a, HI);
  f32x2 B = __builtin_amdgcn_cvt_pk_f32_fp8((int)b, HI);
  f32x2 C = __builtin_amdgcn_cvt_pk_f32_fp8((int)c, HI);
  f32x2 D = __builtin_amdgcn_cvt_pk_f32_fp8((int)d, HI);
  return (A + B) + (C + D);
}

// ---- K0: frag-major W1 tables + W2/Wo transposes + bw -> bf16 table ----------
__global__ void k_prep(const float* __restrict__ wc1, const float* __restrict__ wg1,
                       const float* __restrict__ wc2, const float* __restrict__ wg2,
                       const float* __restrict__ wo,
                       const float* __restrict__ bc1, const float* __restrict__ bg1,
                       const float* __restrict__ bwt,
                       unsigned short* __restrict__ wpb, unsigned short* __restrict__ wpa,
                       unsigned short* __restrict__ wpg,
                       unsigned short* __restrict__ wc2t, unsigned short* __restrict__ wg2t,
                       unsigned short* __restrict__ wot, float* __restrict__ biaspg,
                       unsigned short* __restrict__ bw16, int n8) {
  int t = blockIdx.x * 256 + threadIdx.x;
  if (t < 16384) {          // wpb: NOUT=256
    int blk = t >> 9, n = blk >> 1, s = blk & 1;
    int lane = (t >> 3) & 63, e = t & 7;
    int p = lane >> 4, q = lane & 15;
    int k = 32 * s + 8 * p + e;
    int o = 16 * n + q;
    float v;
    if (o < 64)       v = wc1[k * KH + o];
    else if (o < 128) v = wg1[k * KH + (o - 64)];
    else if (o < 192) v = wc1[(64 + k) * KH + (o - 128)];
    else              v = wg1[(64 + k) * KH + (o - 192)];
    wpb[t] = f2bf(v);
  }
  if (t < 8192) {           // wpa / wpg: NOUT=128
    int blk = t >> 9, n = blk >> 1, s = blk & 1;
    int lane = (t >> 3) & 63, e = t & 7;
    int p = lane >> 4, q = lane & 15;
    int k = 32 * s + 8 * p + e;
    int o = 16 * n + q;
    float va = (o < 64) ? wc1[(192 + k) * KH + o] : wg1[(192 + k) * KH + (o - 64)];
    wpa[t] = f2bf(va);
    float vg = (o < 64) ? wc1[(128 + k) * KH + o] : wg1[(128 + k) * KH + (o - 64)];
    wpg[t] = f2bf(vg);
  }
  if (t < KH * KD) {        // natural B^T [d][k]
    int d = t >> 6, k = t & 63;
    wc2t[t] = f2bf(wc2[k * KD + d]);
    wg2t[t] = f2bf(wg2[k * KD + d]);
    wot[t]  = f2bf(wo[k * KD + d]);
  }
  if (t < 128) biaspg[t] = (t < 64) ? bc1[t] : bg1[t - 64];
  if (t < n8) *(bf16x8*)(bw16 + (long)t * 8) = pack8(bwt + (long)t * 8);
}

// ---- passA: P[r][NOUT] = X[r][0:64] @ Wseg (+bias), fp8 out ------------------
template<int NOUT>
__global__ __launch_bounds__(256) void k_partial(
    const float* __restrict__ X, const unsigned short* __restrict__ wfrag,
    const float* __restrict__ bias, unsigned char* __restrict__ P, int nrows) {
  constexpr int NSH = NOUT * 64;
  __shared__ unsigned short wl[NSH];
  const int tid = threadIdx.x;
  for (int c = tid * 8; c < NSH; c += 256 * 8)
    *(bf16x8*)&wl[c] = *(const bf16x8*)&wfrag[c];
  __syncthreads();
  const int wave = tid >> 6, lane = tid & 63, p = lane >> 4, q = lane & 15;
  const int ntile = (nrows + 63) >> 6;
  for (int tile = blockIdx.x; tile < ntile; tile += gridDim.x) {
    const int r0 = tile * 64 + wave * 16 + q;
    const int r = (r0 < nrows) ? r0 : (nrows - 1);
    bf16x8 b[2];
    b[0] = pack8(X + (long)r * 64 + 8 * p);
    b[1] = pack8(X + (long)r * 64 + 32 + 8 * p);
    unsigned char* dst = P + (long)r0 * NOUT;
#pragma unroll
    for (int n = 0; n < NOUT / 16; n++) {
      f32x4 acc;
      if (bias) acc = (f32x4&)*(const float4*)(bias + 16 * n + 4 * p);
      else      acc = (f32x4){0.f, 0.f, 0.f, 0.f};
#pragma unroll
      for (int s = 0; s < 2; s++) {
        bf16x8 a = *(const bf16x8*)&wl[((n * 2 + s) * 64 + lane) * 8];
        acc = __builtin_amdgcn_mfma_f32_16x16x32_bf16(a, b[s], acc, 0, 0, 0);
      }
      if (r0 < nrows)
        *(unsigned*)(dst + 16 * n + 4 * p) = pk_fp8x4(acc[0], acc[1], acc[2], acc[3]);
    }
  }
}

// ---- CSR build (binned by bi, bins = na) -------------------------------------
__global__ void k_hist(const int* __restrict__ bgr, int* __restrict__ cnt, int ng) {
  int g = blockIdx.x * blockDim.x + threadIdx.x;
  if (g < ng) atomicAdd(&cnt[bgr[3 * g + 1]], 1);
}

__global__ __launch_bounds__(256) void k_scan1(const int* __restrict__ cnt,
                                               int* __restrict__ part,
                                               int* __restrict__ bsum, int n) {
  __shared__ int wsum[4];
  const int tid = threadIdx.x;
  const int i = blockIdx.x * 256 + tid;
  const int lane = tid & 63, w = tid >> 6;
  int orig = (i < n) ? cnt[i] : 0;
  int v = orig;
#pragma unroll
  for (int d = 1; d < 64; d <<= 1) {
    int t = __shfl_up(v, d);
    if (lane >= d) v += t;
  }
  if (lane == 63) wsum[w] = v;
  __syncthreads();
  int add = 0;
  for (int k = 0; k < w; k++) add += wsum[k];
  v += add;
  if (i < n) part[i] = v - orig;
  if (tid == 255) bsum[blockIdx.x] = v;
}

__global__ __launch_bounds__(1024) void k_scan2(const int* __restrict__ bsum,
                                                int* __restrict__ bscan, int nblk) {
  __shared__ int wsum[16];
  const int tid = threadIdx.x;
  const int lane = tid & 63, w = tid >> 6;
  int orig = (tid < nblk) ? bsum[tid] : 0;
  int v = orig;
#pragma unroll
  for (int d = 1; d < 64; d <<= 1) {
    int t = __shfl_up(v, d);
    if (lane >= d) v += t;
  }
  if (lane == 63) wsum[w] = v;
  __syncthreads();
  int add = 0;
  for (int k = 0; k < w; k++) add += wsum[k];
  v += add;
  if (tid < nblk) bscan[tid] = v - orig;
}

__global__ void k_scan3(const int* __restrict__ part, const int* __restrict__ bscan,
                        int* __restrict__ off, int* __restrict__ cur, int n) {
  int i = blockIdx.x * blockDim.x + threadIdx.x;
  if (i < n) {
    off[i] = part[i] + bscan[i >> 8];
    cur[i] = 0;
  }
}

__global__ void k_fill(const int* __restrict__ bgr, const int* __restrict__ off,
                       int* __restrict__ cur, int4* __restrict__ ids4, int ng) {
  int g = blockIdx.x * blockDim.x + threadIdx.x;
  if (g < ng) {
    int ci = bgr[3 * g + 0];
    int bi = bgr[3 * g + 1];
    int bj = bgr[3 * g + 2];
    int slot = atomicAdd(&cur[bi], 1);
    int4 r; r.x = g; r.y = ci; r.z = bj; r.w = bi;
    ids4[off[bi] + slot] = r;
  }
}

// ---- k_agg: fp8 gather -> pk-sum -> silu -> MFMA GEMM2 -> dense bf16 write ----
__global__ __launch_bounds__(256) void k_agg(
    const int4* __restrict__ ids4,
    const unsigned char* __restrict__ PB, const unsigned char* __restrict__ PA,
    const unsigned char* __restrict__ PG,
    const unsigned short* __restrict__ wc2t, const unsigned short* __restrict__ wg2t,
    const float* __restrict__ bc2, const float* __restrict__ bg2,
    const unsigned short* __restrict__ bw16,
    unsigned short* __restrict__ upd2, int ntot) {
  const int tid = threadIdx.x, wave = tid >> 6, lane = tid & 63;
  const int p = lane >> 4, q = lane & 15;

  const int ntile = (ntot + 63) >> 6;
  for (int tile = blockIdx.x; tile < ntile; tile += gridDim.x) {
    const int pos = tile * 64 + wave * 16 + q;
    const int4 r = ids4[(pos < ntot) ? pos : (ntot - 1)];
    const int g = r.x, ci = r.y, bj = r.z, bi = r.w;

    const unsigned char* rb1 = PB + (long)bi * 256;        // [c1|g1|c2|g2] 64B each
    const unsigned char* rb2 = PB + (long)bj * 256 + 128;
    const unsigned char* ra  = PA + (long)ci * 128;        // [c|g]
    const unsigned char* rg  = PG + (long)g  * 128;

    bf16x8 b2c[2], b2g[2];
#pragma unroll
    for (int s = 0; s < 2; s++) {
      const int o8 = 32 * s + 8 * p;
      uint2 v1 = *(const uint2*)(rb1 + o8);
      uint2 v2 = *(const uint2*)(rb2 + o8);
      uint2 v3 = *(const uint2*)(ra + o8);
      uint2 v4 = *(const uint2*)(rg + o8);
      uint2 w1 = *(const uint2*)(rb1 + 64 + o8);
      uint2 w2 = *(const uint2*)(rb2 + 64 + o8);
      uint2 w3 = *(const uint2*)(ra + 64 + o8);
      uint2 w4 = *(const uint2*)(rg + 64 + o8);
      union { unsigned u[4]; bf16x8 v; } uc, ug;
      {
        f32x2 s0 = sumpair_fp8<false>(v1.x, v2.x, v3.x, v4.x);
        f32x2 s1 = sumpair_fp8<true >(v1.x, v2.x, v3.x, v4.x);
        f32x2 s2 = sumpair_fp8<false>(v1.y, v2.y, v3.y, v4.y);
        f32x2 s3 = sumpair_fp8<true >(v1.y, v2.y, v3.y, v4.y);
        uc.u[0] = cvtpk_bf16(silu_(s0[0]), silu_(s0[1]));
        uc.u[1] = cvtpk_bf16(silu_(s1[0]), silu_(s1[1]));
        uc.u[2] = cvtpk_bf16(silu_(s2[0]), silu_(s2[1]));
        uc.u[3] = cvtpk_bf16(silu_(s3[0]), silu_(s3[1]));
      }
      {
        f32x2 s0 = sumpair_fp8<false>(w1.x, w2.x, w3.x, w4.x);
        f32x2 s1 = sumpair_fp8<true >(w1.x, w2.x, w3.x, w4.x);
        f32x2 s2 = sumpair_fp8<false>(w1.y, w2.y, w3.y, w4.y);
        f32x2 s3 = sumpair_fp8<true >(w1.y, w2.y, w3.y, w4.y);
        ug.u[0] = cvtpk_bf16(silu_(s0[0]), silu_(s0[1]));
        ug.u[1] = cvtpk_bf16(silu_(s1[0]), silu_(s1[1]));
        ug.u[2] = cvtpk_bf16(silu_(s2[0]), silu_(s2[1]));
        ug.u[3] = cvtpk_bf16(silu_(s3[0]), silu_(s3[1]));
      }
      b2c[s] = uc.v;
      b2g[s] = ug.v;
    }

    // GEMM2 (transposed): oc[n2][j] = O[d=16n2+4p+j][angle q]
    f32x4 oc[4], og[4];
#pragma unroll
    for (int n2 = 0; n2 < 4; n2++) {
      oc[n2] = (f32x4&)*(const float4*)(bc2 + 16 * n2 + 4 * p);
      og[n2] = (f32x4&)*(const float4*)(bg2 + 16 * n2 + 4 * p);
    }
#pragma unroll
    for (int s = 0; s < 2; s++) {
      const int ko = 32 * s + 8 * p;
#pragma unroll
      for (int n2 = 0; n2 < 4; n2++) {
        bf16x8 a1 = *(const bf16x8*)(wc2t + (q + 16 * n2) * KH + ko);
        oc[n2] = __builtin_amdgcn_mfma_f32_16x16x32_bf16(a1, b2c[s], oc[n2], 0, 0, 0);
        bf16x8 a2 = *(const bf16x8*)(wg2t + (q + 16 * n2) * KH + ko);
        og[n2] = __builtin_amdgcn_mfma_f32_16x16x32_bf16(a2, b2g[s], og[n2], 0, 0, 0);
      }
    }

    // dense write in sorted order: upd2[pos][d] = silu(oc)*sigm(og)*bw[bj][d]
    if (pos < ntot) {
      unsigned short* dst = upd2 + (long)pos * KD;
      const unsigned short* wj = bw16 + (long)bj * KD;
#pragma unroll
      for (int n2 = 0; n2 < 4; n2++) {
        const int d = 16 * n2 + 4 * p;
        ushort4 b = *(const ushort4*)(wj + d);
        float f0 = silu_(oc[n2][0]) * sigm(og[n2][0]) * bf2f(b.x);
        float f1 = silu_(oc[n2][1]) * sigm(og[n2][1]) * bf2f(b.y);
        float f2 = silu_(oc[n2][2]) * sigm(og[n2][2]) * bf2f(b.z);
        float f3 = silu_(oc[n2][3]) * sigm(og[n2][3]) * bf2f(b.w);
        uint2 st;
        st.x = cvtpk_bf16(f0, f1);
        st.y = cvtpk_bf16(f2, f3);
        *(uint2*)(dst + d) = st;
      }
    }
  }
}

// ---- k_aggout: contiguous segment-sum(upd2)*bw[b] -> @Wo + bo + bond -> out
// covers ALL nb bonds; rows >= na have empty segments (pure bo + bond path)
__global__ __launch_bounds__(256) void k_aggout(
    const float* __restrict__ bond, const float* __restrict__ bwt,
    const unsigned short* __restrict__ upd2,
    const int* __restrict__ off, const int* __restrict__ cnt,
    const unsigned short* __restrict__ wot, const float* __restrict__ bo,
    float* __restrict__ out, int na, int nb) {
  const int wave = threadIdx.x >> 6;
  const int lane = threadIdx.x & 63;
  const int r15 = lane & 15;
  const int ck = lane >> 4;
  const int base = blockIdx.x * 64 + wave * 16;
  const int b = base + r15;
  const bool hasseg = (b < na);
  const int bc = hasseg ? b : 0;
  const int o = off[bc];
  const int c = hasseg ? cnt[bc] : 0;
  const int d0 = ck * 8;

  float acc[16];
#pragma unroll
  for (int e = 0; e < 16; e++) acc[e] = 0.0f;

  int it = 0;
  for (; it + 2 <= c; it += 2) {
    const unsigned short* r0 = upd2 + (long)(o + it) * KD;
    const unsigned short* r1 = r0 + KD;
    bf16x8 l0 = *(const bf16x8*)(r0 + d0);
    bf16x8 h0 = *(const bf16x8*)(r0 + 32 + d0);
    bf16x8 l1 = *(const bf16x8*)(r1 + d0);
    bf16x8 h1 = *(const bf16x8*)(r1 + 32 + d0);
#pragma unroll
    for (int e = 0; e < 8; e++) {
      acc[e]     += bf2f((unsigned short)l0[e]) + bf2f((unsigned short)l1[e]);
      acc[8 + e] += bf2f((unsigned short)h0[e]) + bf2f((unsigned short)h1[e]);
    }
  }
  if (it < c) {
    const unsigned short* r0 = upd2 + (long)(o + it) * KD;
    bf16x8 l0 = *(const bf16x8*)(r0 + d0);
    bf16x8 h0 = *(const bf16x8*)(r0 + 32 + d0);
#pragma unroll
    for (int e = 0; e < 8; e++) {
      acc[e]     += bf2f((unsigned short)l0[e]);
      acc[8 + e] += bf2f((unsigned short)h0[e]);
    }
  }

  {  // deferred bw[bi] factor (safe: any b < nb is a valid bwt row)
    const float* w = bwt + (long)((b < nb) ? b : 0) * KD;
    float4 w0 = *(const float4*)(w + d0);
    float4 w1 = *(const float4*)(w + d0 + 4);
    float4 w2 = *(const float4*)(w + 32 + d0);
    float4 w3 = *(const float4*)(w + 32 + d0 + 4);
    acc[0] *= w0.x;  acc[1] *= w0.y;  acc[2] *= w0.z;  acc[3] *= w0.w;
    acc[4] *= w1.x;  acc[5] *= w1.y;  acc[6] *= w1.z;  acc[7] *= w1.w;
    acc[8] *= w2.x;  acc[9] *= w2.y;  acc[10] *= w2.z; acc[11] *= w2.w;
    acc[12] *= w3.x; acc[13] *= w3.y; acc[14] *= w3.z; acc[15] *= w3.w;
  }

  bf16x8 a[2];
#pragma unroll
  for (int e = 0; e < 8; e++) {
    a[0][e] = (short)f2bf(acc[e]);
    a[1][e] = (short)f2bf(acc[8 + e]);
  }

  f32x4 acc2[4];
#pragma unroll
  for (int n = 0; n < 4; n++) {
    float bv = bo[n * 16 + r15];
    acc2[n] = (f32x4){bv, bv, bv, bv};
  }
#pragma unroll
  for (int s = 0; s < 2; s++) {
    const int koff = s * 32 + ck * 8;
#pragma unroll
    for (int n = 0; n < 4; n++) {
      bf16x8 bf = *(const bf16x8*)(wot + (n * 16 + r15) * KH + koff);
      acc2[n] = __builtin_amdgcn_mfma_f32_16x16x32_bf16(a[s], bf, acc2[n], 0, 0, 0);
    }
  }
#pragma unroll
  for (int n = 0; n < 4; n++) {
#pragma unroll
    for (int j = 0; j < 4; j++) {
      const int orow = base + ck * 4 + j;
      if (orow < nb) {
        const int d = n * 16 + r15;
        out[(long)orow * KD + d] = acc2[n][j] + bond[(long)orow * KD + d];
      }
    }
  }
}

extern "C" void kernel_launch(void* const* d_in, const int* in_sizes, int n_in,
                              void* d_out, int out_size, void* d_ws, size_t ws_size,
                              hipStream_t stream) {
  const float* atom = (const float*)d_in[0];
  const float* bond = (const float*)d_in[1];
  const float* bwt  = (const float*)d_in[2];
  const float* ang  = (const float*)d_in[3];
  const int*   bgr  = (const int*)d_in[4];
  const float* wc1 = (const float*)d_in[5];
  const float* bc1 = (const float*)d_in[6];
  const float* wc2 = (const float*)d_in[7];
  const float* bc2 = (const float*)d_in[8];
  const float* wg1 = (const float*)d_in[9];
  const float* bg1 = (const float*)d_in[10];
  const float* wg2 = (const float*)d_in[11];
  const float* bg2 = (const float*)d_in[12];
  const float* wo  = (const float*)d_in[13];
  const float* bo  = (const float*)d_in[14];

  const int na = in_sizes[0] / KD;   // atoms (40000); all bond_graph indices < na
  const int nb = in_sizes[1] / KD;   // bonds (200000)
  const int ng = in_sizes[4] / 3;    // angles (500000)
  float* out = (float*)d_out;

  char* pp = (char*)d_ws;
  auto alloc = [&](size_t bytes) { char* r = pp; pp += (bytes + 255) & ~(size_t)255; return r; };
  unsigned short* wpb  = (unsigned short*)alloc(16384 * 2);
  unsigned short* wpa  = (unsigned short*)alloc(8192 * 2);
  unsigned short* wpg  = (unsigned short*)alloc(8192 * 2);
  unsigned short* wc2t = (unsigned short*)alloc((size_t)KH * KD * 2);
  unsigned short* wg2t = (unsigned short*)alloc((size_t)KH * KD * 2);
  unsigned short* wot  = (unsigned short*)alloc((size_t)KH * KD * 2);
  float* biaspg        = (float*)alloc(128 * 4);
  unsigned short* bw16 = (unsigned short*)alloc((size_t)na * KD * 2);   // 5.1 MB
  unsigned char* PB    = (unsigned char*)alloc((size_t)na * 256);       // 10.2 MB
  unsigned char* PA    = (unsigned char*)alloc((size_t)na * 128);       // 5.1 MB
  unsigned char* PG    = (unsigned char*)alloc((size_t)ng * 128);       // 64 MB
  unsigned short* upd2 = (unsigned short*)alloc((size_t)ng * KD * 2);   // 64 MB
  int* cnt  = (int*)alloc((size_t)na * 4);
  int* cur  = (int*)alloc((size_t)na * 4);
  int* offb = (int*)alloc((size_t)na * 4);
  int* part = (int*)alloc((size_t)na * 4);
  int4* ids4 = (int4*)alloc((size_t)ng * 16);                           // 8 MB
  int* bsum  = (int*)alloc(4096);
  int* bscan = (int*)alloc(4096);

  const int nblk = (na + 255) / 256;   // 157 <= 1024
  const int n8 = na * KD / 8;          // bw16 rows of 8

  hipMemsetAsync(cnt, 0, (size_t)na * 4, stream);

  k_prep<<<(n8 + 255) / 256, 256, 0, stream>>>(wc1, wg1, wc2, wg2, wo, bc1, bg1, bwt,
                                               wpb, wpa, wpg, wc2t, wg2t, wot, biaspg,
                                               bw16, n8);

  const int tb = (na + 63) / 64;       // 625
  k_partial<256><<<tb, 256, 0, stream>>>(bond, wpb, (const float*)nullptr, PB, na);
  k_partial<128><<<tb, 256, 0, stream>>>(atom, wpa, (const float*)nullptr, PA, na);
  const int tg = (ng + 63) / 64;       // 7813
  k_partial<128><<<(tg < 2048 ? tg : 2048), 256, 0, stream>>>(ang, wpg, biaspg, PG, ng);

  k_hist<<<(ng + 255) / 256, 256, 0, stream>>>(bgr, cnt, ng);
  k_scan1<<<nblk, 256, 0, stream>>>(cnt, part, bsum, na);
  k_scan2<<<1, 1024, 0, stream>>>(bsum, bscan, nblk);
  k_scan3<<<nblk, 256, 0, stream>>>(part, bscan, offb, cur, na);
  k_fill<<<(ng + 255) / 256, 256, 0, stream>>>(bgr, offb, cur, ids4, ng);

  k_agg<<<2048, 256, 0, stream>>>(ids4, PB, PA, PG, wc2t, wg2t,
                                  bc2, bg2, bw16, upd2, ng);

  k_aggout<<<(nb + 63) / 64, 256, 0, stream>>>(bond, bwt, upd2, offb, cnt,
                                               wot, bo, out, na, nb);
}

// Round 10
// 335.788 us; speedup vs baseline: 1.0149x; 1.0149x over previous
//
#include <hip/hip_runtime.h>
#include <hip/hip_bf16.h>

static constexpr int KD  = 64;
static constexpr int KH  = 64;

typedef __attribute__((ext_vector_type(8))) short bf16x8;
typedef __attribute__((ext_vector_type(4))) float f32x4;
typedef __attribute__((ext_vector_type(2))) float f32x2;

__device__ inline unsigned short f2bf(float f) {
  union { float f; unsigned u; } uf; uf.f = f;
  unsigned u = uf.u;
  return (unsigned short)((u + 0x7FFFu + ((u >> 16) & 1u)) >> 16);
}
__device__ inline float bf2f(unsigned short h) {
  union { unsigned u; float f; } x; x.u = ((unsigned)h) << 16; return x.f;
}
__device__ inline bf16x8 pack8(const float* p) {
  float4 lo = *(const float4*)p;
  float4 hi = *(const float4*)(p + 4);
  bf16x8 v;
  v[0] = (short)f2bf(lo.x); v[1] = (short)f2bf(lo.y);
  v[2] = (short)f2bf(lo.z); v[3] = (short)f2bf(lo.w);
  v[4] = (short)f2bf(hi.x); v[5] = (short)f2bf(hi.y);
  v[6] = (short)f2bf(hi.z); v[7] = (short)f2bf(hi.w);
  return v;
}
__device__ inline float sigm(float x) { return 1.0f / (1.0f + __expf(-x)); }
__device__ inline float silu_(float x) { return x * sigm(x); }
__device__ inline unsigned pk_fp8x4(float a0, float a1, float a2, float a3) {
  int v = __builtin_amdgcn_cvt_pk_fp8_f32(a0, a1, 0, false);
  v = __builtin_amdgcn_cvt_pk_fp8_f32(a2, a3, v, true);
  return (unsigned)v;
}
__device__ inline unsigned cvtpk_bf16(float lo, float hi) {
  unsigned r;
  asm("v_cvt_pk_bf16_f32 %0, %1, %2" : "=v"(r) : "v"(lo), "v"(hi));
  return r;
}
template<bool HI>
__device__ inline f32x2 sumpair_fp8(unsigned a, unsigned b, unsigned c, unsigned d) {
  f32x2 A = __builtin_amdgcn_cvt_pk_f32_fp8((int)a, HI);
  f32x2 B = __builtin_amdgcn_cvt_pk_f32_fp8((int)b, HI);
  f32x2 C = __builtin_amdgcn_cvt_pk_f32_fp8((int)c, HI);
  f32x2 D = __builtin_amdgcn_cvt_pk_f32_fp8((int)d, HI);
  return (A + B) + (C + D);
}

// ---- K0: frag-major W1 tables + W2/Wo transposes + biases --------------------
__global__ void k_prep(const float* __restrict__ wc1, const float* __restrict__ wg1,
                       const float* __restrict__ wc2, const float* __restrict__ wg2,
                       const float* __restrict__ wo,
                       const float* __restrict__ bc1, const float* __restrict__ bg1,
                       unsigned short* __restrict__ wpb, unsigned short* __restrict__ wpa,
                       unsigned short* __restrict__ wpg,
                       unsigned short* __restrict__ wc2t, unsigned short* __restrict__ wg2t,
                       unsigned short* __restrict__ wot, float* __restrict__ biaspg) {
  int t = blockIdx.x * 256 + threadIdx.x;
  if (t < 16384) {          // wpb: NOUT=256
    int blk = t >> 9, n = blk >> 1, s = blk & 1;
    int lane = (t >> 3) & 63, e = t & 7;
    int p = lane >> 4, q = lane & 15;
    int k = 32 * s + 8 * p + e;
    int o = 16 * n + q;
    float v;
    if (o < 64)       v = wc1[k * KH + o];
    else if (o < 128) v = wg1[k * KH + (o - 64)];
    else if (o < 192) v = wc1[(64 + k) * KH + (o - 128)];
    else              v = wg1[(64 + k) * KH + (o - 192)];
    wpb[t] = f2bf(v);
  }
  if (t < 8192) {           // wpa / wpg: NOUT=128
    int blk = t >> 9, n = blk >> 1, s = blk & 1;
    int lane = (t >> 3) & 63, e = t & 7;
    int p = lane >> 4, q = lane & 15;
    int k = 32 * s + 8 * p + e;
    int o = 16 * n + q;
    float va = (o < 64) ? wc1[(192 + k) * KH + o] : wg1[(192 + k) * KH + (o - 64)];
    wpa[t] = f2bf(va);
    float vg = (o < 64) ? wc1[(128 + k) * KH + o] : wg1[(128 + k) * KH + (o - 64)];
    wpg[t] = f2bf(vg);
  }
  if (t < KH * KD) {        // natural B^T [d][k]
    int d = t >> 6, k = t & 63;
    wc2t[t] = f2bf(wc2[k * KD + d]);
    wg2t[t] = f2bf(wg2[k * KD + d]);
    wot[t]  = f2bf(wo[k * KD + d]);
  }
  if (t < 128) biaspg[t] = (t < 64) ? bc1[t] : bg1[t - 64];
}

// ---- passA: P[row] = X[r][0:64] @ Wseg (+bias), fp8 out ----------------------
// rowstride in bytes. If rank != null, output row index = rank[r0] (sorted PG).
// If bwsrc != null, also pack bwsrc[r0][0:64] as fp8 at +256 (PBX rows).
template<int NOUT>
__global__ __launch_bounds__(256) void k_partial(
    const float* __restrict__ X, const unsigned short* __restrict__ wfrag,
    const float* __restrict__ bias, unsigned char* __restrict__ P, int nrows,
    int rowstride, const int* __restrict__ rank, const float* __restrict__ bwsrc) {
  constexpr int NSH = NOUT * 64;
  __shared__ unsigned short wl[NSH];
  const int tid = threadIdx.x;
  for (int c = tid * 8; c < NSH; c += 256 * 8)
    *(bf16x8*)&wl[c] = *(const bf16x8*)&wfrag[c];
  __syncthreads();
  const int wave = tid >> 6, lane = tid & 63, p = lane >> 4, q = lane & 15;
  const int ntile = (nrows + 63) >> 6;
  for (int tile = blockIdx.x; tile < ntile; tile += gridDim.x) {
    const int r0 = tile * 64 + wave * 16 + q;
    const int r = (r0 < nrows) ? r0 : (nrows - 1);
    bf16x8 b[2];
    b[0] = pack8(X + (long)r * 64 + 8 * p);
    b[1] = pack8(X + (long)r * 64 + 32 + 8 * p);
    const int rr = (rank != nullptr && r0 < nrows) ? rank[r0] : r0;
    unsigned char* dst = P + (long)rr * rowstride;
#pragma unroll
    for (int n = 0; n < NOUT / 16; n++) {
      f32x4 acc;
      if (bias) acc = (f32x4&)*(const float4*)(bias + 16 * n + 4 * p);
      else      acc = (f32x4){0.f, 0.f, 0.f, 0.f};
#pragma unroll
      for (int s = 0; s < 2; s++) {
        bf16x8 a = *(const bf16x8*)&wl[((n * 2 + s) * 64 + lane) * 8];
        acc = __builtin_amdgcn_mfma_f32_16x16x32_bf16(a, b[s], acc, 0, 0, 0);
      }
      if (r0 < nrows)
        *(unsigned*)(dst + 16 * n + 4 * p) = pk_fp8x4(acc[0], acc[1], acc[2], acc[3]);
    }
    if (bwsrc != nullptr && r0 < nrows) {
      // lane (p,q): pack bw[r0][16p..16p+16) -> 16B fp8 at +256+16p
      const float* bw = bwsrc + (long)r0 * 64 + 16 * p;
      float4 w0 = *(const float4*)(bw);
      float4 w1 = *(const float4*)(bw + 4);
      float4 w2 = *(const float4*)(bw + 8);
      float4 w3 = *(const float4*)(bw + 12);
      uint4 pk;
      pk.x = pk_fp8x4(w0.x, w0.y, w0.z, w0.w);
      pk.y = pk_fp8x4(w1.x, w1.y, w1.z, w1.w);
      pk.z = pk_fp8x4(w2.x, w2.y, w2.z, w2.w);
      pk.w = pk_fp8x4(w3.x, w3.y, w3.z, w3.w);
      *(uint4*)(dst + 256 + 16 * p) = pk;
    }
  }
}

// ---- CSR build (binned by bi, bins = na) -------------------------------------
__global__ void k_hist(const int* __restrict__ bgr, int* __restrict__ cnt, int ng) {
  int g = blockIdx.x * blockDim.x + threadIdx.x;
  if (g < ng) atomicAdd(&cnt[bgr[3 * g + 1]], 1);
}

__global__ __launch_bounds__(256) void k_scan1(const int* __restrict__ cnt,
                                               int* __restrict__ part,
                                               int* __restrict__ bsum, int n) {
  __shared__ int wsum[4];
  const int tid = threadIdx.x;
  const int i = blockIdx.x * 256 + tid;
  const int lane = tid & 63, w = tid >> 6;
  int orig = (i < n) ? cnt[i] : 0;
  int v = orig;
#pragma unroll
  for (int d = 1; d < 64; d <<= 1) {
    int t = __shfl_up(v, d);
    if (lane >= d) v += t;
  }
  if (lane == 63) wsum[w] = v;
  __syncthreads();
  int add = 0;
  for (int k = 0; k < w; k++) add += wsum[k];
  v += add;
  if (i < n) part[i] = v - orig;
  if (tid == 255) bsum[blockIdx.x] = v;
}

__global__ __launch_bounds__(1024) void k_scan2(const int* __restrict__ bsum,
                                                int* __restrict__ bscan, int nblk) {
  __shared__ int wsum[16];
  const int tid = threadIdx.x;
  const int lane = tid & 63, w = tid >> 6;
  int orig = (tid < nblk) ? bsum[tid] : 0;
  int v = orig;
#pragma unroll
  for (int d = 1; d < 64; d <<= 1) {
    int t = __shfl_up(v, d);
    if (lane >= d) v += t;
  }
  if (lane == 63) wsum[w] = v;
  __syncthreads();
  int add = 0;
  for (int k = 0; k < w; k++) add += wsum[k];
  v += add;
  if (tid < nblk) bscan[tid] = v - orig;
}

__global__ void k_scan3(const int* __restrict__ part, const int* __restrict__ bscan,
                        int* __restrict__ off, int* __restrict__ cur, int n) {
  int i = blockIdx.x * blockDim.x + threadIdx.x;
  if (i < n) {
    off[i] = part[i] + bscan[i >> 8];
    cur[i] = 0;
  }
}

// fill: rank[g] (dense) + sorted records {ci,bj,bi}
__global__ void k_fill(const int* __restrict__ bgr, const int* __restrict__ off,
                       int* __restrict__ cur, int4* __restrict__ ids4,
                       int* __restrict__ rank, int ng) {
  int g = blockIdx.x * blockDim.x + threadIdx.x;
  if (g < ng) {
    int ci = bgr[3 * g + 0];
    int bi = bgr[3 * g + 1];
    int bj = bgr[3 * g + 2];
    int slot = atomicAdd(&cur[bi], 1);
    int posn = off[bi] + slot;
    rank[g] = posn;
    int4 r; r.x = ci; r.y = bj; r.z = bi; r.w = 0;
    ids4[posn] = r;
  }
}

// ---- k_agg: PG dense + PBX/PA gathers -> silu -> MFMA GEMM2 -> dense write ----
__global__ __launch_bounds__(256) void k_agg(
    const int4* __restrict__ ids4,
    const unsigned char* __restrict__ PBX, const unsigned char* __restrict__ PA,
    const unsigned char* __restrict__ PG,
    const unsigned short* __restrict__ wc2t, const unsigned short* __restrict__ wg2t,
    const float* __restrict__ bc2, const float* __restrict__ bg2,
    unsigned short* __restrict__ upd2, int ntot) {
  const int tid = threadIdx.x, wave = tid >> 6, lane = tid & 63;
  const int p = lane >> 4, q = lane & 15;

  const int ntile = (ntot + 63) >> 6;
  for (int tile = blockIdx.x; tile < ntile; tile += gridDim.x) {
    const int pos = tile * 64 + wave * 16 + q;
    const int posc = (pos < ntot) ? pos : (ntot - 1);
    const int4 r = ids4[posc];
    const int ci = r.x, bj = r.y, bi = r.z;

    const unsigned char* rb1 = PBX + (long)bi * 320;        // [c1|g1] at +0/+64
    const unsigned char* rb2 = PBX + (long)bj * 320 + 128;  // [c2|g2] at +0/+64
    const unsigned char* ra  = PA + (long)ci * 128;         // [c|g]
    const unsigned char* rg  = PG + (long)posc * 128;       // DENSE (rank-sorted)

    bf16x8 b2c[2], b2g[2];
#pragma unroll
    for (int s = 0; s < 2; s++) {
      const int o8 = 32 * s + 8 * p;
      uint2 v1 = *(const uint2*)(rb1 + o8);
      uint2 v2 = *(const uint2*)(rb2 + o8);
      uint2 v3 = *(const uint2*)(ra + o8);
      uint2 v4 = *(const uint2*)(rg + o8);
      uint2 w1 = *(const uint2*)(rb1 + 64 + o8);
      uint2 w2 = *(const uint2*)(rb2 + 64 + o8);
      uint2 w3 = *(const uint2*)(ra + 64 + o8);
      uint2 w4 = *(const uint2*)(rg + 64 + o8);
      union { unsigned u[4]; bf16x8 v; } uc, ug;
      {
        f32x2 s0 = sumpair_fp8<false>(v1.x, v2.x, v3.x, v4.x);
        f32x2 s1 = sumpair_fp8<true >(v1.x, v2.x, v3.x, v4.x);
        f32x2 s2 = sumpair_fp8<false>(v1.y, v2.y, v3.y, v4.y);
        f32x2 s3 = sumpair_fp8<true >(v1.y, v2.y, v3.y, v4.y);
        uc.u[0] = cvtpk_bf16(silu_(s0[0]), silu_(s0[1]));
        uc.u[1] = cvtpk_bf16(silu_(s1[0]), silu_(s1[1]));
        uc.u[2] = cvtpk_bf16(silu_(s2[0]), silu_(s2[1]));
        uc.u[3] = cvtpk_bf16(silu_(s3[0]), silu_(s3[1]));
      }
      {
        f32x2 s0 = sumpair_fp8<false>(w1.x, w2.x, w3.x, w4.x);
        f32x2 s1 = sumpair_fp8<true >(w1.x, w2.x, w3.x, w4.x);
        f32x2 s2 = sumpair_fp8<false>(w1.y, w2.y, w3.y, w4.y);
        f32x2 s3 = sumpair_fp8<true >(w1.y, w2.y, w3.y, w4.y);
        ug.u[0] = cvtpk_bf16(silu_(s0[0]), silu_(s0[1]));
        ug.u[1] = cvtpk_bf16(silu_(s1[0]), silu_(s1[1]));
        ug.u[2] = cvtpk_bf16(silu_(s2[0]), silu_(s2[1]));
        ug.u[3] = cvtpk_bf16(silu_(s3[0]), silu_(s3[1]));
      }
      b2c[s] = uc.v;
      b2g[s] = ug.v;
    }

    // GEMM2 (transposed): oc[n2][j] = O[d=16n2+4p+j][angle q]
    f32x4 oc[4], og[4];
#pragma unroll
    for (int n2 = 0; n2 < 4; n2++) {
      oc[n2] = (f32x4&)*(const float4*)(bc2 + 16 * n2 + 4 * p);
      og[n2] = (f32x4&)*(const float4*)(bg2 + 16 * n2 + 4 * p);
    }
#pragma unroll
    for (int s = 0; s < 2; s++) {
      const int ko = 32 * s + 8 * p;
#pragma unroll
      for (int n2 = 0; n2 < 4; n2++) {
        bf16x8 a1 = *(const bf16x8*)(wc2t + (q + 16 * n2) * KH + ko);
        oc[n2] = __builtin_amdgcn_mfma_f32_16x16x32_bf16(a1, b2c[s], oc[n2], 0, 0, 0);
        bf16x8 a2 = *(const bf16x8*)(wg2t + (q + 16 * n2) * KH + ko);
        og[n2] = __builtin_amdgcn_mfma_f32_16x16x32_bf16(a2, b2g[s], og[n2], 0, 0, 0);
      }
    }

    // dense write: upd2[pos][d] = silu(oc)*sigm(og)*bw_fp8[bj][d]
    if (pos < ntot) {
      unsigned short* dst = upd2 + (long)pos * KD;
      const unsigned char* pbw = PBX + (long)bj * 320 + 256;
#pragma unroll
      for (int n2 = 0; n2 < 4; n2++) {
        const int d = 16 * n2 + 4 * p;
        unsigned wj = *(const unsigned*)(pbw + d);
        f32x2 blo = __builtin_amdgcn_cvt_pk_f32_fp8((int)wj, false);
        f32x2 bhi = __builtin_amdgcn_cvt_pk_f32_fp8((int)wj, true);
        float f0 = silu_(oc[n2][0]) * sigm(og[n2][0]) * blo[0];
        float f1 = silu_(oc[n2][1]) * sigm(og[n2][1]) * blo[1];
        float f2 = silu_(oc[n2][2]) * sigm(og[n2][2]) * bhi[0];
        float f3 = silu_(oc[n2][3]) * sigm(og[n2][3]) * bhi[1];
        uint2 st;
        st.x = cvtpk_bf16(f0, f1);
        st.y = cvtpk_bf16(f2, f3);
        *(uint2*)(dst + d) = st;
      }
    }
  }
}

// ---- k_aggout: contiguous segment-sum(upd2)*bw[b] -> @Wo + bo + bond -> out ---
__global__ __launch_bounds__(256) void k_aggout(
    const float* __restrict__ bond, const float* __restrict__ bwt,
    const unsigned short* __restrict__ upd2,
    const int* __restrict__ off, const int* __restrict__ cnt,
    const unsigned short* __restrict__ wot, const float* __restrict__ bo,
    float* __restrict__ out, int na, int nb) {
  const int wave = threadIdx.x >> 6;
  const int lane = threadIdx.x & 63;
  const int r15 = lane & 15;
  const int ck = lane >> 4;
  const int base = blockIdx.x * 64 + wave * 16;
  const int b = base + r15;
  const bool hasseg = (b < na);
  const int bc = hasseg ? b : 0;
  const int o = off[bc];
  const int c = hasseg ? cnt[bc] : 0;
  const int d0 = ck * 8;

  float acc[16];
#pragma unroll
  for (int e = 0; e < 16; e++) acc[e] = 0.0f;

  int it = 0;
  for (; it + 2 <= c; it += 2) {
    const unsigned short* r0 = upd2 + (long)(o + it) * KD;
    const unsigned short* r1 = r0 + KD;
    bf16x8 l0 = *(const bf16x8*)(r0 + d0);
    bf16x8 h0 = *(const bf16x8*)(r0 + 32 + d0);
    bf16x8 l1 = *(const bf16x8*)(r1 + d0);
    bf16x8 h1 = *(const bf16x8*)(r1 + 32 + d0);
#pragma unroll
    for (int e = 0; e < 8; e++) {
      acc[e]     += bf2f((unsigned short)l0[e]) + bf2f((unsigned short)l1[e]);
      acc[8 + e] += bf2f((unsigned short)h0[e]) + bf2f((unsigned short)h1[e]);
    }
  }
  if (it < c) {
    const unsigned short* r0 = upd2 + (long)(o + it) * KD;
    bf16x8 l0 = *(const bf16x8*)(r0 + d0);
    bf16x8 h0 = *(const bf16x8*)(r0 + 32 + d0);
#pragma unroll
    for (int e = 0; e < 8; e++) {
      acc[e]     += bf2f((unsigned short)l0[e]);
      acc[8 + e] += bf2f((unsigned short)h0[e]);
    }
  }

  if (hasseg) {  // deferred bw[bi] factor, f32 precision; skip entirely for b>=na
    const float* w = bwt + (long)b * KD;
    float4 w0 = *(const float4*)(w + d0);
    float4 w1 = *(const float4*)(w + d0 + 4);
    float4 w2 = *(const float4*)(w + 32 + d0);
    float4 w3 = *(const float4*)(w + 32 + d0 + 4);
    acc[0] *= w0.x;  acc[1] *= w0.y;  acc[2] *= w0.z;  acc[3] *= w0.w;
    acc[4] *= w1.x;  acc[5] *= w1.y;  acc[6] *= w1.z;  acc[7] *= w1.w;
    acc[8] *= w2.x;  acc[9] *= w2.y;  acc[10] *= w2.z; acc[11] *= w2.w;
    acc[12] *= w3.x; acc[13] *= w3.y; acc[14] *= w3.z; acc[15] *= w3.w;
  }

  bf16x8 a[2];
#pragma unroll
  for (int e = 0; e < 8; e++) {
    a[0][e] = (short)f2bf(acc[e]);
    a[1][e] = (short)f2bf(acc[8 + e]);
  }

  f32x4 acc2[4];
#pragma unroll
  for (int n = 0; n < 4; n++) {
    float bv = bo[n * 16 + r15];
    acc2[n] = (f32x4){bv, bv, bv, bv};
  }
#pragma unroll
  for (int s = 0; s < 2; s++) {
    const int koff = s * 32 + ck * 8;
#pragma unroll
    for (int n = 0; n < 4; n++) {
      bf16x8 bf = *(const bf16x8*)(wot + (n * 16 + r15) * KH + koff);
      acc2[n] = __builtin_amdgcn_mfma_f32_16x16x32_bf16(a[s], bf, acc2[n], 0, 0, 0);
    }
  }
#pragma unroll
  for (int n = 0; n < 4; n++) {
#pragma unroll
    for (int j = 0; j < 4; j++) {
      const int orow = base + ck * 4 + j;
      if (orow < nb) {
        const int d = n * 16 + r15;
        out[(long)orow * KD + d] = acc2[n][j] + bond[(long)orow * KD + d];
      }
    }
  }
}

extern "C" void kernel_launch(void* const* d_in, const int* in_sizes, int n_in,
                              void* d_out, int out_size, void* d_ws, size_t ws_size,
                              hipStream_t stream) {
  const float* atom = (const float*)d_in[0];
  const float* bond = (const float*)d_in[1];
  const float* bwt  = (const float*)d_in[2];
  const float* ang  = (const float*)d_in[3];
  const int*   bgr  = (const int*)d_in[4];
  const float* wc1 = (const float*)d_in[5];
  const float* bc1 = (const float*)d_in[6];
  const float* wc2 = (const float*)d_in[7];
  const float* bc2 = (const float*)d_in[8];
  const float* wg1 = (const float*)d_in[9];
  const float* bg1 = (const float*)d_in[10];
  const float* wg2 = (const float*)d_in[11];
  const float* bg2 = (const float*)d_in[12];
  const float* wo  = (const float*)d_in[13];
  const float* bo  = (const float*)d_in[14];

  const int na = in_sizes[0] / KD;   // atoms (40000); all bond_graph indices < na
  const int nb = in_sizes[1] / KD;   // bonds (200000)
  const int ng = in_sizes[4] / 3;    // angles (500000)
  float* out = (float*)d_out;

  char* pp = (char*)d_ws;
  auto alloc = [&](size_t bytes) { char* r = pp; pp += (bytes + 255) & ~(size_t)255; return r; };
  unsigned short* wpb  = (unsigned short*)alloc(16384 * 2);
  unsigned short* wpa  = (unsigned short*)alloc(8192 * 2);
  unsigned short* wpg  = (unsigned short*)alloc(8192 * 2);
  unsigned short* wc2t = (unsigned short*)alloc((size_t)KH * KD * 2);
  unsigned short* wg2t = (unsigned short*)alloc((size_t)KH * KD * 2);
  unsigned short* wot  = (unsigned short*)alloc((size_t)KH * KD * 2);
  float* biaspg        = (float*)alloc(128 * 4);
  unsigned char* PBX   = (unsigned char*)alloc((size_t)na * 320);       // 12.8 MB
  unsigned char* PA    = (unsigned char*)alloc((size_t)na * 128);       // 5.1 MB
  unsigned char* PG    = (unsigned char*)alloc((size_t)ng * 128);       // 64 MB (rank-sorted)
  unsigned short* upd2 = (unsigned short*)alloc((size_t)ng * KD * 2);   // 64 MB
  int* cnt  = (int*)alloc((size_t)na * 4);
  int* cur  = (int*)alloc((size_t)na * 4);
  int* offb = (int*)alloc((size_t)na * 4);
  int* part = (int*)alloc((size_t)na * 4);
  int* rank = (int*)alloc((size_t)ng * 4);                              // 2 MB
  int4* ids4 = (int4*)alloc((size_t)ng * 16);                           // 8 MB
  int* bsum  = (int*)alloc(4096);
  int* bscan = (int*)alloc(4096);

  const int nblk = (na + 255) / 256;   // 157 <= 1024

  hipMemsetAsync(cnt, 0, (size_t)na * 4, stream);

  k_prep<<<64, 256, 0, stream>>>(wc1, wg1, wc2, wg2, wo, bc1, bg1,
                                 wpb, wpa, wpg, wc2t, wg2t, wot, biaspg);

  // CSR first (rank needed by the angle partial pass)
  k_hist<<<(ng + 255) / 256, 256, 0, stream>>>(bgr, cnt, ng);
  k_scan1<<<nblk, 256, 0, stream>>>(cnt, part, bsum, na);
  k_scan2<<<1, 1024, 0, stream>>>(bsum, bscan, nblk);
  k_scan3<<<nblk, 256, 0, stream>>>(part, bscan, offb, cur, na);
  k_fill<<<(ng + 255) / 256, 256, 0, stream>>>(bgr, offb, cur, ids4, rank, ng);

  const int tb = (na + 63) / 64;       // 625
  k_partial<256><<<tb, 256, 0, stream>>>(bond, wpb, (const float*)nullptr, PBX, na,
                                         320, (const int*)nullptr, bwt);
  k_partial<128><<<tb, 256, 0, stream>>>(atom, wpa, (const float*)nullptr, PA, na,
                                         128, (const int*)nullptr, (const float*)nullptr);
  const int tg = (ng + 63) / 64;       // 7813
  k_partial<128><<<(tg < 2048 ? tg : 2048), 256, 0, stream>>>(ang, wpg, biaspg, PG, ng,
                                         128, rank, (const float*)nullptr);

  k_agg<<<2048, 256, 0, stream>>>(ids4, PBX, PA, PG, wc2t, wg2t,
                                  bc2, bg2, upd2, ng);

  k_aggout<<<(nb + 63) / 64, 256, 0, stream>>>(bond, bwt, upd2, offb, cnt,
                                               wot, bo, out, na, nb);
}

// Round 11
// 322.235 us; speedup vs baseline: 1.0576x; 1.0421x over previous
//
#include <hip/hip_runtime.h>
#include <hip/hip_bf16.h>

static constexpr int KD  = 64;
static constexpr int KH  = 64;

typedef __attribute__((ext_vector_type(8))) short bf16x8;
typedef __attribute__((ext_vector_type(4))) float f32x4;
typedef __attribute__((ext_vector_type(2))) float f32x2;

__device__ inline unsigned short f2bf(float f) {
  union { float f; unsigned u; } uf; uf.f = f;
  unsigned u = uf.u;
  return (unsigned short)((u + 0x7FFFu + ((u >> 16) & 1u)) >> 16);
}
__device__ inline float bf2f(unsigned short h) {
  union { unsigned u; float f; } x; x.u = ((unsigned)h) << 16; return x.f;
}
__device__ inline bf16x8 pack8(const float* p) {
  float4 lo = *(const float4*)p;
  float4 hi = *(const float4*)(p + 4);
  bf16x8 v;
  v[0] = (short)f2bf(lo.x); v[1] = (short)f2bf(lo.y);
  v[2] = (short)f2bf(lo.z); v[3] = (short)f2bf(lo.w);
  v[4] = (short)f2bf(hi.x); v[5] = (short)f2bf(hi.y);
  v[6] = (short)f2bf(hi.z); v[7] = (short)f2bf(hi.w);
  return v;
}
__device__ inline float sigm(float x) { return 1.0f / (1.0f + __expf(-x)); }
__device__ inline float silu_(float x) { return x * sigm(x); }
__device__ inline unsigned pk_fp8x4(float a0, float a1, float a2, float a3) {
  int v = __builtin_amdgcn_cvt_pk_fp8_f32(a0, a1, 0, false);
  v = __builtin_amdgcn_cvt_pk_fp8_f32(a2, a3, v, true);
  return (unsigned)v;
}
__device__ inline unsigned cvtpk_bf16(float lo, float hi) {
  unsigned r;
  asm("v_cvt_pk_bf16_f32 %0, %1, %2" : "=v"(r) : "v"(lo), "v"(hi));
  return r;
}
template<bool HI>
__device__ inline f32x2 sumpair_fp8(unsigned a, unsigned b, unsigned c, unsigned d) {
  f32x2 A = __builtin_amdgcn_cvt_pk_f32_fp8((int)a, HI);
  f32x2 B = __builtin_amdgcn_cvt_pk_f32_fp8((int)b, HI);
  f32x2 C = __builtin_amdgcn_cvt_pk_f32_fp8((int)c, HI);
  f32x2 D = __builtin_amdgcn_cvt_pk_f32_fp8((int)d, HI);
  return (A + B) + (C + D);
}

// ---- K0: frag-major W1 tables + W2/Wo transposes + biases + HISTOGRAM --------
__global__ void k_prep(const float* __restrict__ wc1, const float* __restrict__ wg1,
                       const float* __restrict__ wc2, const float* __restrict__ wg2,
                       const float* __restrict__ wo,
                       const float* __restrict__ bc1, const float* __restrict__ bg1,
                       unsigned short* __restrict__ wpb, unsigned short* __restrict__ wpa,
                       unsigned short* __restrict__ wpg,
                       unsigned short* __restrict__ wc2t, unsigned short* __restrict__ wg2t,
                       unsigned short* __restrict__ wot, float* __restrict__ biaspg,
                       const int* __restrict__ bgr, int* __restrict__ cnt, int ng) {
  int t = blockIdx.x * 256 + threadIdx.x;
  if (t < 16384) {          // wpb: NOUT=256
    int blk = t >> 9, n = blk >> 1, s = blk & 1;
    int lane = (t >> 3) & 63, e = t & 7;
    int p = lane >> 4, q = lane & 15;
    int k = 32 * s + 8 * p + e;
    int o = 16 * n + q;
    float v;
    if (o < 64)       v = wc1[k * KH + o];
    else if (o < 128) v = wg1[k * KH + (o - 64)];
    else if (o < 192) v = wc1[(64 + k) * KH + (o - 128)];
    else              v = wg1[(64 + k) * KH + (o - 192)];
    wpb[t] = f2bf(v);
  }
  if (t < 8192) {           // wpa / wpg: NOUT=128
    int blk = t >> 9, n = blk >> 1, s = blk & 1;
    int lane = (t >> 3) & 63, e = t & 7;
    int p = lane >> 4, q = lane & 15;
    int k = 32 * s + 8 * p + e;
    int o = 16 * n + q;
    float va = (o < 64) ? wc1[(192 + k) * KH + o] : wg1[(192 + k) * KH + (o - 64)];
    wpa[t] = f2bf(va);
    float vg = (o < 64) ? wc1[(128 + k) * KH + o] : wg1[(128 + k) * KH + (o - 64)];
    wpg[t] = f2bf(vg);
  }
  if (t < KH * KD) {        // natural B^T [d][k]
    int d = t >> 6, k = t & 63;
    wc2t[t] = f2bf(wc2[k * KD + d]);
    wg2t[t] = f2bf(wg2[k * KD + d]);
    wot[t]  = f2bf(wo[k * KD + d]);
  }
  if (t < 128) biaspg[t] = (t < 64) ? bc1[t] : bg1[t - 64];
  if (t < ng) atomicAdd(&cnt[bgr[3 * t + 1]], 1);
}

// ---- passA (bond/atom): P[r] = X[r] @ Wseg, fp8 out; optional packed fp8 bw --
template<int NOUT>
__global__ __launch_bounds__(256) void k_partial(
    const float* __restrict__ X, const unsigned short* __restrict__ wfrag,
    const float* __restrict__ bias, unsigned char* __restrict__ P, int nrows,
    int rowstride, const float* __restrict__ bwsrc) {
  constexpr int NSH = NOUT * 64;
  __shared__ unsigned short wl[NSH];
  const int tid = threadIdx.x;
  for (int c = tid * 8; c < NSH; c += 256 * 8)
    *(bf16x8*)&wl[c] = *(const bf16x8*)&wfrag[c];
  __syncthreads();
  const int wave = tid >> 6, lane = tid & 63, p = lane >> 4, q = lane & 15;
  const int ntile = (nrows + 63) >> 6;
  for (int tile = blockIdx.x; tile < ntile; tile += gridDim.x) {
    const int r0 = tile * 64 + wave * 16 + q;
    const int r = (r0 < nrows) ? r0 : (nrows - 1);
    bf16x8 b[2];
    b[0] = pack8(X + (long)r * 64 + 8 * p);
    b[1] = pack8(X + (long)r * 64 + 32 + 8 * p);
    unsigned char* dst = P + (long)r0 * rowstride;
#pragma unroll
    for (int n = 0; n < NOUT / 16; n++) {
      f32x4 acc;
      if (bias) acc = (f32x4&)*(const float4*)(bias + 16 * n + 4 * p);
      else      acc = (f32x4){0.f, 0.f, 0.f, 0.f};
#pragma unroll
      for (int s = 0; s < 2; s++) {
        bf16x8 a = *(const bf16x8*)&wl[((n * 2 + s) * 64 + lane) * 8];
        acc = __builtin_amdgcn_mfma_f32_16x16x32_bf16(a, b[s], acc, 0, 0, 0);
      }
      if (r0 < nrows)
        *(unsigned*)(dst + 16 * n + 4 * p) = pk_fp8x4(acc[0], acc[1], acc[2], acc[3]);
    }
    if (bwsrc != nullptr && r0 < nrows) {
      const float* bw = bwsrc + (long)r0 * 64 + 16 * p;
      float4 w0 = *(const float4*)(bw);
      float4 w1 = *(const float4*)(bw + 4);
      float4 w2 = *(const float4*)(bw + 8);
      float4 w3 = *(const float4*)(bw + 12);
      uint4 pk;
      pk.x = pk_fp8x4(w0.x, w0.y, w0.z, w0.w);
      pk.y = pk_fp8x4(w1.x, w1.y, w1.z, w1.w);
      pk.z = pk_fp8x4(w2.x, w2.y, w2.z, w2.w);
      pk.w = pk_fp8x4(w3.x, w3.y, w3.z, w3.w);
      *(uint4*)(dst + 256 + 16 * p) = pk;
    }
  }
}

// ---- scans -------------------------------------------------------------------
__global__ __launch_bounds__(256) void k_scan1(const int* __restrict__ cnt,
                                               int* __restrict__ part,
                                               int* __restrict__ bsum, int n) {
  __shared__ int wsum[4];
  const int tid = threadIdx.x;
  const int i = blockIdx.x * 256 + tid;
  const int lane = tid & 63, w = tid >> 6;
  int orig = (i < n) ? cnt[i] : 0;
  int v = orig;
#pragma unroll
  for (int d = 1; d < 64; d <<= 1) {
    int t = __shfl_up(v, d);
    if (lane >= d) v += t;
  }
  if (lane == 63) wsum[w] = v;
  __syncthreads();
  int add = 0;
  for (int k = 0; k < w; k++) add += wsum[k];
  v += add;
  if (i < n) part[i] = v - orig;
  if (tid == 255) bsum[blockIdx.x] = v;
}

__global__ __launch_bounds__(1024) void k_scan2(const int* __restrict__ bsum,
                                                int* __restrict__ bscan, int nblk) {
  __shared__ int wsum[16];
  const int tid = threadIdx.x;
  const int lane = tid & 63, w = tid >> 6;
  int orig = (tid < nblk) ? bsum[tid] : 0;
  int v = orig;
#pragma unroll
  for (int d = 1; d < 64; d <<= 1) {
    int t = __shfl_up(v, d);
    if (lane >= d) v += t;
  }
  if (lane == 63) wsum[w] = v;
  __syncthreads();
  int add = 0;
  for (int k = 0; k < w; k++) add += wsum[k];
  v += add;
  if (tid < nblk) bscan[tid] = v - orig;
}

__global__ void k_scan3(const int* __restrict__ part, const int* __restrict__ bscan,
                        int* __restrict__ off, int* __restrict__ cur, int n) {
  int i = blockIdx.x * blockDim.x + threadIdx.x;
  if (i < n) {
    off[i] = part[i] + bscan[i >> 8];
    cur[i] = 0;
  }
}

// ---- angle partial pass + FUSED fill: PG row written at rank, ids4 emitted ----
__global__ __launch_bounds__(256) void k_partial_ang(
    const float* __restrict__ X, const unsigned short* __restrict__ wfrag,
    const float* __restrict__ bias, const int* __restrict__ bgr,
    const int* __restrict__ off, int* __restrict__ cur,
    unsigned char* __restrict__ PG, int4* __restrict__ ids4, int ng) {
  __shared__ unsigned short wl[128 * 64];
  const int tid = threadIdx.x;
  for (int c = tid * 8; c < 128 * 64; c += 256 * 8)
    *(bf16x8*)&wl[c] = *(const bf16x8*)&wfrag[c];
  __syncthreads();
  const int wave = tid >> 6, lane = tid & 63, p = lane >> 4, q = lane & 15;
  const int ntile = (ng + 63) >> 6;
  for (int tile = blockIdx.x; tile < ntile; tile += gridDim.x) {
    const int r0 = tile * 64 + wave * 16 + q;
    const bool ok = r0 < ng;
    const int r = ok ? r0 : (ng - 1);
    bf16x8 b[2];
    b[0] = pack8(X + (long)r * 64 + 8 * p);
    b[1] = pack8(X + (long)r * 64 + 32 + 8 * p);
    int rr = 0;
    if (p == 0 && ok) {
      int ci = bgr[3 * r0 + 0];
      int bi = bgr[3 * r0 + 1];
      int bj = bgr[3 * r0 + 2];
      int slot = atomicAdd(&cur[bi], 1);
      rr = off[bi] + slot;
      int4 rec; rec.x = ci; rec.y = bj; rec.z = bi; rec.w = 0;
      ids4[rr] = rec;
    }
    rr = __shfl(rr, q);                 // broadcast rank from the p==0 lane
    unsigned char* dst = PG + (long)rr * 128;
#pragma unroll
    for (int n = 0; n < 8; n++) {
      f32x4 acc = (f32x4&)*(const float4*)(bias + 16 * n + 4 * p);
#pragma unroll
      for (int s = 0; s < 2; s++) {
        bf16x8 a = *(const bf16x8*)&wl[((n * 2 + s) * 64 + lane) * 8];
        acc = __builtin_amdgcn_mfma_f32_16x16x32_bf16(a, b[s], acc, 0, 0, 0);
      }
      if (ok)
        *(unsigned*)(dst + 16 * n + 4 * p) = pk_fp8x4(acc[0], acc[1], acc[2], acc[3]);
    }
  }
}

// ---- k_agg: 2-tile ILP; gathers for both tiles issued before any compute -----
struct GR {
  uint2 v[8];     // [s*4 + src] src: 0=rb1 1=rb2 2=ra 3=rg  (core half)
  uint2 w[8];     // gate half
  unsigned bw[4];
};

__device__ inline GR gather_tile(const unsigned char* __restrict__ PBX,
                                 const unsigned char* __restrict__ PA,
                                 const unsigned char* __restrict__ PG,
                                 int4 r, int posc, int p) {
  GR g;
  const unsigned char* rb1 = PBX + (long)r.z * 384;         // line 0: c1|g1
  const unsigned char* rb2 = PBX + (long)r.y * 384 + 128;   // line 1: c2|g2
  const unsigned char* ra  = PA + (long)r.x * 128;
  const unsigned char* rg  = PG + (long)posc * 128;         // dense (rank-sorted)
#pragma unroll
  for (int s = 0; s < 2; s++) {
    const int o8 = 32 * s + 8 * p;
    g.v[s * 4 + 0] = *(const uint2*)(rb1 + o8);
    g.v[s * 4 + 1] = *(const uint2*)(rb2 + o8);
    g.v[s * 4 + 2] = *(const uint2*)(ra + o8);
    g.v[s * 4 + 3] = *(const uint2*)(rg + o8);
    g.w[s * 4 + 0] = *(const uint2*)(rb1 + 64 + o8);
    g.w[s * 4 + 1] = *(const uint2*)(rb2 + 64 + o8);
    g.w[s * 4 + 2] = *(const uint2*)(ra + 64 + o8);
    g.w[s * 4 + 3] = *(const uint2*)(rg + 64 + o8);
  }
  const unsigned char* pbw = PBX + (long)r.y * 384 + 256 + 4 * p;  // line 2: bw fp8
#pragma unroll
  for (int n2 = 0; n2 < 4; n2++)
    g.bw[n2] = *(const unsigned*)(pbw + 16 * n2);
  return g;
}

__device__ inline void process_tile(const GR& g, int pos, int ntot, int p, int q,
    const unsigned short* __restrict__ wc2t, const unsigned short* __restrict__ wg2t,
    const float* __restrict__ bc2, const float* __restrict__ bg2,
    unsigned short* __restrict__ upd2) {
  bf16x8 b2c[2], b2g[2];
#pragma unroll
  for (int s = 0; s < 2; s++) {
    union { unsigned u[4]; bf16x8 v; } uc, ug;
    {
      f32x2 s0 = sumpair_fp8<false>(g.v[s*4+0].x, g.v[s*4+1].x, g.v[s*4+2].x, g.v[s*4+3].x);
      f32x2 s1 = sumpair_fp8<true >(g.v[s*4+0].x, g.v[s*4+1].x, g.v[s*4+2].x, g.v[s*4+3].x);
      f32x2 s2 = sumpair_fp8<false>(g.v[s*4+0].y, g.v[s*4+1].y, g.v[s*4+2].y, g.v[s*4+3].y);
      f32x2 s3 = sumpair_fp8<true >(g.v[s*4+0].y, g.v[s*4+1].y, g.v[s*4+2].y, g.v[s*4+3].y);
      uc.u[0] = cvtpk_bf16(silu_(s0[0]), silu_(s0[1]));
      uc.u[1] = cvtpk_bf16(silu_(s1[0]), silu_(s1[1]));
      uc.u[2] = cvtpk_bf16(silu_(s2[0]), silu_(s2[1]));
      uc.u[3] = cvtpk_bf16(silu_(s3[0]), silu_(s3[1]));
    }
    {
      f32x2 s0 = sumpair_fp8<false>(g.w[s*4+0].x, g.w[s*4+1].x, g.w[s*4+2].x, g.w[s*4+3].x);
      f32x2 s1 = sumpair_fp8<true >(g.w[s*4+0].x, g.w[s*4+1].x, g.w[s*4+2].x, g.w[s*4+3].x);
      f32x2 s2 = sumpair_fp8<false>(g.w[s*4+0].y, g.w[s*4+1].y, g.w[s*4+2].y, g.w[s*4+3].y);
      f32x2 s3 = sumpair_fp8<true >(g.w[s*4+0].y, g.w[s*4+1].y, g.w[s*4+2].y, g.w[s*4+3].y);
      ug.u[0] = cvtpk_bf16(silu_(s0[0]), silu_(s0[1]));
      ug.u[1] = cvtpk_bf16(silu_(s1[0]), silu_(s1[1]));
      ug.u[2] = cvtpk_bf16(silu_(s2[0]), silu_(s2[1]));
      ug.u[3] = cvtpk_bf16(silu_(s3[0]), silu_(s3[1]));
    }
    b2c[s] = uc.v;
    b2g[s] = ug.v;
  }

  f32x4 oc[4], og[4];
#pragma unroll
  for (int n2 = 0; n2 < 4; n2++) {
    oc[n2] = (f32x4&)*(const float4*)(bc2 + 16 * n2 + 4 * p);
    og[n2] = (f32x4&)*(const float4*)(bg2 + 16 * n2 + 4 * p);
  }
#pragma unroll
  for (int s = 0; s < 2; s++) {
    const int ko = 32 * s + 8 * p;
#pragma unroll
    for (int n2 = 0; n2 < 4; n2++) {
      bf16x8 a1 = *(const bf16x8*)(wc2t + (q + 16 * n2) * KH + ko);
      oc[n2] = __builtin_amdgcn_mfma_f32_16x16x32_bf16(a1, b2c[s], oc[n2], 0, 0, 0);
      bf16x8 a2 = *(const bf16x8*)(wg2t + (q + 16 * n2) * KH + ko);
      og[n2] = __builtin_amdgcn_mfma_f32_16x16x32_bf16(a2, b2g[s], og[n2], 0, 0, 0);
    }
  }

  if (pos < ntot) {
    unsigned short* dst = upd2 + (long)pos * KD;
#pragma unroll
    for (int n2 = 0; n2 < 4; n2++) {
      const int d = 16 * n2 + 4 * p;
      f32x2 blo = __builtin_amdgcn_cvt_pk_f32_fp8((int)g.bw[n2], false);
      f32x2 bhi = __builtin_amdgcn_cvt_pk_f32_fp8((int)g.bw[n2], true);
      float f0 = silu_(oc[n2][0]) * sigm(og[n2][0]) * blo[0];
      float f1 = silu_(oc[n2][1]) * sigm(og[n2][1]) * blo[1];
      float f2 = silu_(oc[n2][2]) * sigm(og[n2][2]) * bhi[0];
      float f3 = silu_(oc[n2][3]) * sigm(og[n2][3]) * bhi[1];
      uint2 st;
      st.x = cvtpk_bf16(f0, f1);
      st.y = cvtpk_bf16(f2, f3);
      *(uint2*)(dst + d) = st;
    }
  }
}

__global__ __launch_bounds__(256) void k_agg(
    const int4* __restrict__ ids4,
    const unsigned char* __restrict__ PBX, const unsigned char* __restrict__ PA,
    const unsigned char* __restrict__ PG,
    const unsigned short* __restrict__ wc2t, const unsigned short* __restrict__ wg2t,
    const float* __restrict__ bc2, const float* __restrict__ bg2,
    unsigned short* __restrict__ upd2, int ntot) {
  const int tid = threadIdx.x, wave = tid >> 6, lane = tid & 63;
  const int p = lane >> 4, q = lane & 15;
  const int posA = blockIdx.x * 128 + wave * 16 + q;
  const int posB = posA + 64;
  const int posAc = (posA < ntot) ? posA : (ntot - 1);
  const int posBc = (posB < ntot) ? posB : (ntot - 1);
  const int4 rA = ids4[posAc];
  const int4 rB = ids4[posBc];
  GR gA = gather_tile(PBX, PA, PG, rA, posAc, p);
  GR gB = gather_tile(PBX, PA, PG, rB, posBc, p);
  process_tile(gA, posA, ntot, p, q, wc2t, wg2t, bc2, bg2, upd2);
  process_tile(gB, posB, ntot, p, q, wc2t, wg2t, bc2, bg2, upd2);
}

// ---- k_aggout: contiguous segment-sum(upd2)*bw[b] -> @Wo + bo + bond -> out ---
__global__ __launch_bounds__(256) void k_aggout(
    const float* __restrict__ bond, const float* __restrict__ bwt,
    const unsigned short* __restrict__ upd2,
    const int* __restrict__ off, const int* __restrict__ cnt,
    const unsigned short* __restrict__ wot, const float* __restrict__ bo,
    float* __restrict__ out, int na, int nb) {
  const int wave = threadIdx.x >> 6;
  const int lane = threadIdx.x & 63;
  const int r15 = lane & 15;
  const int ck = lane >> 4;
  const int base = blockIdx.x * 64 + wave * 16;
  const int b = base + r15;
  const bool hasseg = (b < na);
  const int bc = hasseg ? b : 0;
  const int o = off[bc];
  const int c = hasseg ? cnt[bc] : 0;
  const int d0 = ck * 8;

  float acc[16];
#pragma unroll
  for (int e = 0; e < 16; e++) acc[e] = 0.0f;

  int it = 0;
  for (; it + 2 <= c; it += 2) {
    const unsigned short* r0 = upd2 + (long)(o + it) * KD;
    const unsigned short* r1 = r0 + KD;
    bf16x8 l0 = *(const bf16x8*)(r0 + d0);
    bf16x8 h0 = *(const bf16x8*)(r0 + 32 + d0);
    bf16x8 l1 = *(const bf16x8*)(r1 + d0);
    bf16x8 h1 = *(const bf16x8*)(r1 + 32 + d0);
#pragma unroll
    for (int e = 0; e < 8; e++) {
      acc[e]     += bf2f((unsigned short)l0[e]) + bf2f((unsigned short)l1[e]);
      acc[8 + e] += bf2f((unsigned short)h0[e]) + bf2f((unsigned short)h1[e]);
    }
  }
  if (it < c) {
    const unsigned short* r0 = upd2 + (long)(o + it) * KD;
    bf16x8 l0 = *(const bf16x8*)(r0 + d0);
    bf16x8 h0 = *(const bf16x8*)(r0 + 32 + d0);
#pragma unroll
    for (int e = 0; e < 8; e++) {
      acc[e]     += bf2f((unsigned short)l0[e]);
      acc[8 + e] += bf2f((unsigned short)h0[e]);
    }
  }

  if (hasseg) {
    const float* w = bwt + (long)b * KD;
    float4 w0 = *(const float4*)(w + d0);
    float4 w1 = *(const float4*)(w + d0 + 4);
    float4 w2 = *(const float4*)(w + 32 + d0);
    float4 w3 = *(const float4*)(w + 32 + d0 + 4);
    acc[0] *= w0.x;  acc[1] *= w0.y;  acc[2] *= w0.z;  acc[3] *= w0.w;
    acc[4] *= w1.x;  acc[5] *= w1.y;  acc[6] *= w1.z;  acc[7] *= w1.w;
    acc[8] *= w2.x;  acc[9] *= w2.y;  acc[10] *= w2.z; acc[11] *= w2.w;
    acc[12] *= w3.x; acc[13] *= w3.y; acc[14] *= w3.z; acc[15] *= w3.w;
  }

  bf16x8 a[2];
#pragma unroll
  for (int e = 0; e < 8; e++) {
    a[0][e] = (short)f2bf(acc[e]);
    a[1][e] = (short)f2bf(acc[8 + e]);
  }

  f32x4 acc2[4];
#pragma unroll
  for (int n = 0; n < 4; n++) {
    float bv = bo[n * 16 + r15];
    acc2[n] = (f32x4){bv, bv, bv, bv};
  }
#pragma unroll
  for (int s = 0; s < 2; s++) {
    const int koff = s * 32 + ck * 8;
#pragma unroll
    for (int n = 0; n < 4; n++) {
      bf16x8 bf = *(const bf16x8*)(wot + (n * 16 + r15) * KH + koff);
      acc2[n] = __builtin_amdgcn_mfma_f32_16x16x32_bf16(a[s], bf, acc2[n], 0, 0, 0);
    }
  }
#pragma unroll
  for (int n = 0; n < 4; n++) {
#pragma unroll
    for (int j = 0; j < 4; j++) {
      const int orow = base + ck * 4 + j;
      if (orow < nb) {
        const int d = n * 16 + r15;
        out[(long)orow * KD + d] = acc2[n][j] + bond[(long)orow * KD + d];
      }
    }
  }
}

extern "C" void kernel_launch(void* const* d_in, const int* in_sizes, int n_in,
                              void* d_out, int out_size, void* d_ws, size_t ws_size,
                              hipStream_t stream) {
  const float* atom = (const float*)d_in[0];
  const float* bond = (const float*)d_in[1];
  const float* bwt  = (const float*)d_in[2];
  const float* ang  = (const float*)d_in[3];
  const int*   bgr  = (const int*)d_in[4];
  const float* wc1 = (const float*)d_in[5];
  const float* bc1 = (const float*)d_in[6];
  const float* wc2 = (const float*)d_in[7];
  const float* bc2 = (const float*)d_in[8];
  const float* wg1 = (const float*)d_in[9];
  const float* bg1 = (const float*)d_in[10];
  const float* wg2 = (const float*)d_in[11];
  const float* bg2 = (const float*)d_in[12];
  const float* wo  = (const float*)d_in[13];
  const float* bo  = (const float*)d_in[14];

  const int na = in_sizes[0] / KD;   // atoms (40000); all bond_graph indices < na
  const int nb = in_sizes[1] / KD;   // bonds (200000)
  const int ng = in_sizes[4] / 3;    // angles (500000)
  float* out = (float*)d_out;

  char* pp = (char*)d_ws;
  auto alloc = [&](size_t bytes) { char* r = pp; pp += (bytes + 255) & ~(size_t)255; return r; };
  unsigned short* wpb  = (unsigned short*)alloc(16384 * 2);
  unsigned short* wpa  = (unsigned short*)alloc(8192 * 2);
  unsigned short* wpg  = (unsigned short*)alloc(8192 * 2);
  unsigned short* wc2t = (unsigned short*)alloc((size_t)KH * KD * 2);
  unsigned short* wg2t = (unsigned short*)alloc((size_t)KH * KD * 2);
  unsigned short* wot  = (unsigned short*)alloc((size_t)KH * KD * 2);
  float* biaspg        = (float*)alloc(128 * 4);
  unsigned char* PBX   = (unsigned char*)alloc((size_t)na * 384);       // 15.4 MB, line-aligned rows
  unsigned char* PA    = (unsigned char*)alloc((size_t)na * 128);       // 5.1 MB
  unsigned char* PG    = (unsigned char*)alloc((size_t)ng * 128);       // 64 MB (rank-sorted)
  unsigned short* upd2 = (unsigned short*)alloc((size_t)ng * KD * 2);   // 64 MB
  int* cnt  = (int*)alloc((size_t)na * 4);
  int* cur  = (int*)alloc((size_t)na * 4);
  int* offb = (int*)alloc((size_t)na * 4);
  int* part = (int*)alloc((size_t)na * 4);
  int4* ids4 = (int4*)alloc((size_t)ng * 16);                           // 8 MB
  int* bsum  = (int*)alloc(4096);
  int* bscan = (int*)alloc(4096);

  const int nblk = (na + 255) / 256;   // 157 <= 1024

  hipMemsetAsync(cnt, 0, (size_t)na * 4, stream);

  // prep + histogram in one grid
  k_prep<<<(ng + 255) / 256, 256, 0, stream>>>(wc1, wg1, wc2, wg2, wo, bc1, bg1,
                                               wpb, wpa, wpg, wc2t, wg2t, wot, biaspg,
                                               bgr, cnt, ng);
  k_scan1<<<nblk, 256, 0, stream>>>(cnt, part, bsum, na);
  k_scan2<<<1, 1024, 0, stream>>>(bsum, bscan, nblk);
  k_scan3<<<nblk, 256, 0, stream>>>(part, bscan, offb, cur, na);

  const int tb = (na + 63) / 64;       // 625
  k_partial<256><<<tb, 256, 0, stream>>>(bond, wpb, (const float*)nullptr, PBX, na,
                                         384, bwt);
  k_partial<128><<<tb, 256, 0, stream>>>(atom, wpa, (const float*)nullptr, PA, na,
                                         128, (const float*)nullptr);
  const int tg = (ng + 63) / 64;       // 7813
  k_partial_ang<<<(tg < 2048 ? tg : 2048), 256, 0, stream>>>(ang, wpg, biaspg, bgr,
                                                             offb, cur, PG, ids4, ng);

  k_agg<<<(ng + 127) / 128, 256, 0, stream>>>(ids4, PBX, PA, PG, wc2t, wg2t,
                                              bc2, bg2, upd2, ng);

  k_aggout<<<(nb + 63) / 64, 256, 0, stream>>>(bond, bwt, upd2, offb, cnt,
                                               wot, bo, out, na, nb);
}

// Round 12
// 313.687 us; speedup vs baseline: 1.0864x; 1.0273x over previous
//
#include <hip/hip_runtime.h>
#include <hip/hip_bf16.h>

static constexpr int KD  = 64;
static constexpr int KH  = 64;

typedef __attribute__((ext_vector_type(8))) short bf16x8;
typedef __attribute__((ext_vector_type(4))) float f32x4;
typedef __attribute__((ext_vector_type(2))) float f32x2;

__device__ inline unsigned short f2bf(float f) {
  union { float f; unsigned u; } uf; uf.f = f;
  unsigned u = uf.u;
  return (unsigned short)((u + 0x7FFFu + ((u >> 16) & 1u)) >> 16);
}
__device__ inline float bf2f(unsigned short h) {
  union { unsigned u; float f; } x; x.u = ((unsigned)h) << 16; return x.f;
}
__device__ inline bf16x8 pack8(const float* p) {
  float4 lo = *(const float4*)p;
  float4 hi = *(const float4*)(p + 4);
  bf16x8 v;
  v[0] = (short)f2bf(lo.x); v[1] = (short)f2bf(lo.y);
  v[2] = (short)f2bf(lo.z); v[3] = (short)f2bf(lo.w);
  v[4] = (short)f2bf(hi.x); v[5] = (short)f2bf(hi.y);
  v[6] = (short)f2bf(hi.z); v[7] = (short)f2bf(hi.w);
  return v;
}
__device__ inline float sigm(float x) { return 1.0f / (1.0f + __expf(-x)); }
__device__ inline float silu_(float x) { return x * sigm(x); }
__device__ inline unsigned pk_fp8x4(float a0, float a1, float a2, float a3) {
  int v = __builtin_amdgcn_cvt_pk_fp8_f32(a0, a1, 0, false);
  v = __builtin_amdgcn_cvt_pk_fp8_f32(a2, a3, v, true);
  return (unsigned)v;
}
__device__ inline unsigned cvtpk_bf16(float lo, float hi) {
  unsigned r;
  asm("v_cvt_pk_bf16_f32 %0, %1, %2" : "=v"(r) : "v"(lo), "v"(hi));
  return r;
}
template<bool HI>
__device__ inline f32x2 sum3_fp8(unsigned a, unsigned b, unsigned c) {
  f32x2 A = __builtin_amdgcn_cvt_pk_f32_fp8((int)a, HI);
  f32x2 B = __builtin_amdgcn_cvt_pk_f32_fp8((int)b, HI);
  f32x2 C = __builtin_amdgcn_cvt_pk_f32_fp8((int)c, HI);
  return (A + B) + C;
}

// ---- K0: frag-major W1 tables + sigma-permuted W2 + natural Wo + biases + hist
// sigma(k') = 32*(k'>>5) + 16*((k'>>2)&1) + 4*((k'>>3)&3) + (k'&3)  [R4-verified]
__global__ void k_prep(const float* __restrict__ wc1, const float* __restrict__ wg1,
                       const float* __restrict__ wc2, const float* __restrict__ wg2,
                       const float* __restrict__ wo,
                       const float* __restrict__ bc1, const float* __restrict__ bg1,
                       unsigned short* __restrict__ wpb, unsigned short* __restrict__ wpa,
                       unsigned short* __restrict__ wpg,
                       unsigned short* __restrict__ wc2t, unsigned short* __restrict__ wg2t,
                       unsigned short* __restrict__ wot, float* __restrict__ biaspg,
                       const int* __restrict__ bgr, int* __restrict__ cnt, int ng) {
  int t = blockIdx.x * 256 + threadIdx.x;
  if (t < 16384) {          // wpb: NOUT=256 (bond slots 1+2, core+gate)
    int blk = t >> 9, n = blk >> 1, s = blk & 1;
    int lane = (t >> 3) & 63, e = t & 7;
    int p = lane >> 4, q = lane & 15;
    int k = 32 * s + 8 * p + e;
    int o = 16 * n + q;
    float v;
    if (o < 64)       v = wc1[k * KH + o];
    else if (o < 128) v = wg1[k * KH + (o - 64)];
    else if (o < 192) v = wc1[(64 + k) * KH + (o - 128)];
    else              v = wg1[(64 + k) * KH + (o - 192)];
    wpb[t] = f2bf(v);
  }
  if (t < 8192) {           // wpa / wpg: NOUT=128 (atom rows 192:256, angle rows 128:192)
    int blk = t >> 9, n = blk >> 1, s = blk & 1;
    int lane = (t >> 3) & 63, e = t & 7;
    int p = lane >> 4, q = lane & 15;
    int k = 32 * s + 8 * p + e;
    int o = 16 * n + q;
    float va = (o < 64) ? wc1[(192 + k) * KH + o] : wg1[(192 + k) * KH + (o - 64)];
    wpa[t] = f2bf(va);
    float vg = (o < 64) ? wc1[(128 + k) * KH + o] : wg1[(128 + k) * KH + (o - 64)];
    wpg[t] = f2bf(vg);
  }
  if (t < KH * KD) {
    int d = t >> 6, kp = t & 63;
    int h = 32 * (kp >> 5) + 16 * ((kp >> 2) & 1) + 4 * ((kp >> 3) & 3) + (kp & 3);
    wc2t[t] = f2bf(wc2[h * KD + d]);   // sigma-permuted [d][k']
    wg2t[t] = f2bf(wg2[h * KD + d]);
    wot[t]  = f2bf(wo[kp * KD + d]);   // natural [d][k]
  }
  if (t < 128) biaspg[t] = (t < 64) ? bc1[t] : bg1[t - 64];
  if (t < ng) atomicAdd(&cnt[bgr[3 * t + 1]], 1);
}

// ---- passA (bond/atom): P[r] = X[r] @ Wseg, fp8 out; optional packed fp8 bw --
template<int NOUT>
__global__ __launch_bounds__(256) void k_partial(
    const float* __restrict__ X, const unsigned short* __restrict__ wfrag,
    unsigned char* __restrict__ P, int nrows,
    int rowstride, const float* __restrict__ bwsrc) {
  constexpr int NSH = NOUT * 64;
  __shared__ unsigned short wl[NSH];
  const int tid = threadIdx.x;
  for (int c = tid * 8; c < NSH; c += 256 * 8)
    *(bf16x8*)&wl[c] = *(const bf16x8*)&wfrag[c];
  __syncthreads();
  const int wave = tid >> 6, lane = tid & 63, p = lane >> 4, q = lane & 15;
  const int ntile = (nrows + 63) >> 6;
  for (int tile = blockIdx.x; tile < ntile; tile += gridDim.x) {
    const int r0 = tile * 64 + wave * 16 + q;
    const int r = (r0 < nrows) ? r0 : (nrows - 1);
    bf16x8 b[2];
    b[0] = pack8(X + (long)r * 64 + 8 * p);
    b[1] = pack8(X + (long)r * 64 + 32 + 8 * p);
    unsigned char* dst = P + (long)r0 * rowstride;
#pragma unroll
    for (int n = 0; n < NOUT / 16; n++) {
      f32x4 acc = (f32x4){0.f, 0.f, 0.f, 0.f};
#pragma unroll
      for (int s = 0; s < 2; s++) {
        bf16x8 a = *(const bf16x8*)&wl[((n * 2 + s) * 64 + lane) * 8];
        acc = __builtin_amdgcn_mfma_f32_16x16x32_bf16(a, b[s], acc, 0, 0, 0);
      }
      if (r0 < nrows)
        *(unsigned*)(dst + 16 * n + 4 * p) = pk_fp8x4(acc[0], acc[1], acc[2], acc[3]);
    }
    if (bwsrc != nullptr && r0 < nrows) {
      const float* bw = bwsrc + (long)r0 * 64 + 16 * p;
      float4 w0 = *(const float4*)(bw);
      float4 w1 = *(const float4*)(bw + 4);
      float4 w2 = *(const float4*)(bw + 8);
      float4 w3 = *(const float4*)(bw + 12);
      uint4 pk;
      pk.x = pk_fp8x4(w0.x, w0.y, w0.z, w0.w);
      pk.y = pk_fp8x4(w1.x, w1.y, w1.z, w1.w);
      pk.z = pk_fp8x4(w2.x, w2.y, w2.z, w2.w);
      pk.w = pk_fp8x4(w3.x, w3.y, w3.z, w3.w);
      *(uint4*)(dst + 256 + 16 * p) = pk;
    }
  }
}

// ---- scans -------------------------------------------------------------------
__global__ __launch_bounds__(256) void k_scan1(const int* __restrict__ cnt,
                                               int* __restrict__ part,
                                               int* __restrict__ bsum, int n) {
  __shared__ int wsum[4];
  const int tid = threadIdx.x;
  const int i = blockIdx.x * 256 + tid;
  const int lane = tid & 63, w = tid >> 6;
  int orig = (i < n) ? cnt[i] : 0;
  int v = orig;
#pragma unroll
  for (int d = 1; d < 64; d <<= 1) {
    int t = __shfl_up(v, d);
    if (lane >= d) v += t;
  }
  if (lane == 63) wsum[w] = v;
  __syncthreads();
  int add = 0;
  for (int k = 0; k < w; k++) add += wsum[k];
  v += add;
  if (i < n) part[i] = v - orig;
  if (tid == 255) bsum[blockIdx.x] = v;
}

__global__ __launch_bounds__(1024) void k_scan2(const int* __restrict__ bsum,
                                                int* __restrict__ bscan, int nblk) {
  __shared__ int wsum[16];
  const int tid = threadIdx.x;
  const int lane = tid & 63, w = tid >> 6;
  int orig = (tid < nblk) ? bsum[tid] : 0;
  int v = orig;
#pragma unroll
  for (int d = 1; d < 64; d <<= 1) {
    int t = __shfl_up(v, d);
    if (lane >= d) v += t;
  }
  if (lane == 63) wsum[w] = v;
  __syncthreads();
  int add = 0;
  for (int k = 0; k < w; k++) add += wsum[k];
  v += add;
  if (tid < nblk) bscan[tid] = v - orig;
}

__global__ void k_scan3(const int* __restrict__ part, const int* __restrict__ bscan,
                        int* __restrict__ off, int* __restrict__ cur, int n) {
  int i = blockIdx.x * blockDim.x + threadIdx.x;
  if (i < n) {
    off[i] = part[i] + bscan[i >> 8];
    cur[i] = 0;
  }
}

// ---- k_fused: angle GEMM1 (f32 in-register) + fp8 partial sums + silu
//               + sigma-permuted GEMM2 + epilogue -> upd2[rank] --------------
__global__ __launch_bounds__(256) void k_fused(
    const float* __restrict__ ang, const unsigned short* __restrict__ wfrag,
    const float* __restrict__ biaspg, const int* __restrict__ bgr,
    const int* __restrict__ off, int* __restrict__ cur,
    const unsigned char* __restrict__ PBX, const unsigned char* __restrict__ PA,
    const unsigned short* __restrict__ wc2t, const unsigned short* __restrict__ wg2t,
    const float* __restrict__ bc2, const float* __restrict__ bg2,
    unsigned short* __restrict__ upd2, int ng) {
  __shared__ unsigned short wl[128 * 64];
  const int tid = threadIdx.x;
  for (int c = tid * 8; c < 128 * 64; c += 256 * 8)
    *(bf16x8*)&wl[c] = *(const bf16x8*)&wfrag[c];
  __syncthreads();
  const int wave = tid >> 6, lane = tid & 63, p = lane >> 4, q = lane & 15;
  const int ntile = (ng + 63) >> 6;
  for (int tile = blockIdx.x; tile < ntile; tile += gridDim.x) {
    const int g0 = tile * 64 + wave * 16 + q;
    const bool ok = g0 < ng;
    const int g = ok ? g0 : (ng - 1);
    const int ci = bgr[3 * g + 0];
    const int bi = bgr[3 * g + 1];
    const int bj = bgr[3 * g + 2];

    // rank via CSR cursor (p==0 lane of each angle), broadcast across p
    int rr = 0;
    if (p == 0 && ok) {
      int slot = atomicAdd(&cur[bi], 1);
      rr = off[bi] + slot;
    }
    rr = __shfl(rr, q);

    // issue scattered partial gathers early (fp8)
    const unsigned char* rb1 = PBX + (long)bi * 384;        // [c1|g1] +0/+64
    const unsigned char* rb2 = PBX + (long)bj * 384 + 128;  // [c2|g2] +0/+64, bw at +128
    const unsigned char* ra  = PA + (long)ci * 128;         // [c|g]
    unsigned uc1[4], uc2[4], uc3[4], ug1[4], ug2[4], ug3[4], ubw[4];
#pragma unroll
    for (int n = 0; n < 4; n++) {
      const int o = 16 * n + 4 * p;
      uc1[n] = *(const unsigned*)(rb1 + o);
      ug1[n] = *(const unsigned*)(rb1 + 64 + o);
      uc2[n] = *(const unsigned*)(rb2 + o);
      ug2[n] = *(const unsigned*)(rb2 + 64 + o);
      uc3[n] = *(const unsigned*)(ra + o);
      ug3[n] = *(const unsigned*)(ra + 64 + o);
      ubw[n] = *(const unsigned*)(rb2 + 128 + o);
    }

    // GEMM1: angle hidden slice, f32 accumulators (lane holds h=16n+4p+j, angle q)
    bf16x8 b[2];
    b[0] = pack8(ang + (long)g * 64 + 8 * p);
    b[1] = pack8(ang + (long)g * 64 + 32 + 8 * p);
    f32x4 hc[4], hg[4];
#pragma unroll
    for (int n = 0; n < 4; n++) {
      hc[n] = (f32x4&)*(const float4*)(biaspg + 16 * n + 4 * p);
      hg[n] = (f32x4&)*(const float4*)(biaspg + 64 + 16 * n + 4 * p);
    }
#pragma unroll
    for (int s = 0; s < 2; s++) {
#pragma unroll
      for (int n = 0; n < 4; n++) {
        bf16x8 a = *(const bf16x8*)&wl[((n * 2 + s) * 64 + lane) * 8];
        hc[n] = __builtin_amdgcn_mfma_f32_16x16x32_bf16(a, b[s], hc[n], 0, 0, 0);
      }
#pragma unroll
      for (int n = 0; n < 4; n++) {
        bf16x8 a = *(const bf16x8*)&wl[(((4 + n) * 2 + s) * 64 + lane) * 8];
        hg[n] = __builtin_amdgcn_mfma_f32_16x16x32_bf16(a, b[s], hg[n], 0, 0, 0);
      }
    }

    // add PB1 + PB2 + PA partials (fp8 decode) into the f32 hidden
#pragma unroll
    for (int n = 0; n < 4; n++) {
      f32x2 lo = sum3_fp8<false>(uc1[n], uc2[n], uc3[n]);
      f32x2 hi = sum3_fp8<true >(uc1[n], uc2[n], uc3[n]);
      hc[n][0] += lo[0]; hc[n][1] += lo[1]; hc[n][2] += hi[0]; hc[n][3] += hi[1];
      f32x2 glo = sum3_fp8<false>(ug1[n], ug2[n], ug3[n]);
      f32x2 ghi = sum3_fp8<true >(ug1[n], ug2[n], ug3[n]);
      hg[n][0] += glo[0]; hg[n][1] += glo[1]; hg[n][2] += ghi[0]; hg[n][3] += ghi[1];
    }

    // silu + sigma-assembly of GEMM2 B-fragments from OWN accumulators
    bf16x8 b2c[2], b2g[2];
#pragma unroll
    for (int s2 = 0; s2 < 2; s2++) {
      union { unsigned u[4]; bf16x8 v; } uc_, ug_;
#pragma unroll
      for (int eh = 0; eh < 4; eh++) {
        const int e0 = 2 * eh;
        const int n = 2 * s2 + (e0 >> 2), j = e0 & 3;
        uc_.u[eh] = cvtpk_bf16(silu_(hc[n][j]), silu_(hc[n][j + 1]));
        ug_.u[eh] = cvtpk_bf16(silu_(hg[n][j]), silu_(hg[n][j + 1]));
      }
      b2c[s2] = uc_.v;
      b2g[s2] = ug_.v;
    }

    // GEMM2 (sigma-permuted W2): oc[n2][j] = O[d=16n2+4p+j][angle q]
    f32x4 oc[4], og[4];
#pragma unroll
    for (int n2 = 0; n2 < 4; n2++) {
      oc[n2] = (f32x4&)*(const float4*)(bc2 + 16 * n2 + 4 * p);
      og[n2] = (f32x4&)*(const float4*)(bg2 + 16 * n2 + 4 * p);
    }
#pragma unroll
    for (int s2 = 0; s2 < 2; s2++) {
      const int ko = 32 * s2 + 8 * p;
#pragma unroll
      for (int n2 = 0; n2 < 4; n2++) {
        bf16x8 a1 = *(const bf16x8*)(wc2t + (q + 16 * n2) * KH + ko);
        oc[n2] = __builtin_amdgcn_mfma_f32_16x16x32_bf16(a1, b2c[s2], oc[n2], 0, 0, 0);
        bf16x8 a2 = *(const bf16x8*)(wg2t + (q + 16 * n2) * KH + ko);
        og[n2] = __builtin_amdgcn_mfma_f32_16x16x32_bf16(a2, b2g[s2], og[n2], 0, 0, 0);
      }
    }

    // epilogue: upd2[rank][d] = silu(oc)*sigm(og)*bw_fp8[bj][d]
    if (ok) {
      unsigned short* dst = upd2 + (long)rr * KD;
#pragma unroll
      for (int n2 = 0; n2 < 4; n2++) {
        const int d = 16 * n2 + 4 * p;
        f32x2 blo = __builtin_amdgcn_cvt_pk_f32_fp8((int)ubw[n2], false);
        f32x2 bhi = __builtin_amdgcn_cvt_pk_f32_fp8((int)ubw[n2], true);
        float f0 = silu_(oc[n2][0]) * sigm(og[n2][0]) * blo[0];
        float f1 = silu_(oc[n2][1]) * sigm(og[n2][1]) * blo[1];
        float f2 = silu_(oc[n2][2]) * sigm(og[n2][2]) * bhi[0];
        float f3 = silu_(oc[n2][3]) * sigm(og[n2][3]) * bhi[1];
        uint2 st;
        st.x = cvtpk_bf16(f0, f1);
        st.y = cvtpk_bf16(f2, f3);
        *(uint2*)(dst + d) = st;
      }
    }
  }
}

// ---- k_aggout: contiguous segment-sum(upd2)*bw[b] -> @Wo + bo + bond -> out ---
__global__ __launch_bounds__(256) void k_aggout(
    const float* __restrict__ bond, const float* __restrict__ bwt,
    const unsigned short* __restrict__ upd2,
    const int* __restrict__ off, const int* __restrict__ cnt,
    const unsigned short* __restrict__ wot, const float* __restrict__ bo,
    float* __restrict__ out, int na, int nb) {
  const int wave = threadIdx.x >> 6;
  const int lane = threadIdx.x & 63;
  const int r15 = lane & 15;
  const int ck = lane >> 4;
  const int base = blockIdx.x * 64 + wave * 16;
  const int b = base + r15;
  const bool hasseg = (b < na);
  const int bc = hasseg ? b : 0;
  const int o = off[bc];
  const int c = hasseg ? cnt[bc] : 0;
  const int d0 = ck * 8;

  float acc[16];
#pragma unroll
  for (int e = 0; e < 16; e++) acc[e] = 0.0f;

  int it = 0;
  for (; it + 2 <= c; it += 2) {
    const unsigned short* r0 = upd2 + (long)(o + it) * KD;
    const unsigned short* r1 = r0 + KD;
    bf16x8 l0 = *(const bf16x8*)(r0 + d0);
    bf16x8 h0 = *(const bf16x8*)(r0 + 32 + d0);
    bf16x8 l1 = *(const bf16x8*)(r1 + d0);
    bf16x8 h1 = *(const bf16x8*)(r1 + 32 + d0);
#pragma unroll
    for (int e = 0; e < 8; e++) {
      acc[e]     += bf2f((unsigned short)l0[e]) + bf2f((unsigned short)l1[e]);
      acc[8 + e] += bf2f((unsigned short)h0[e]) + bf2f((unsigned short)h1[e]);
    }
  }
  if (it < c) {
    const unsigned short* r0 = upd2 + (long)(o + it) * KD;
    bf16x8 l0 = *(const bf16x8*)(r0 + d0);
    bf16x8 h0 = *(const bf16x8*)(r0 + 32 + d0);
#pragma unroll
    for (int e = 0; e < 8; e++) {
      acc[e]     += bf2f((unsigned short)l0[e]);
      acc[8 + e] += bf2f((unsigned short)h0[e]);
    }
  }

  if (hasseg) {
    const float* w = bwt + (long)b * KD;
    float4 w0 = *(const float4*)(w + d0);
    float4 w1 = *(const float4*)(w + d0 + 4);
    float4 w2 = *(const float4*)(w + 32 + d0);
    float4 w3 = *(const float4*)(w + 32 + d0 + 4);
    acc[0] *= w0.x;  acc[1] *= w0.y;  acc[2] *= w0.z;  acc[3] *= w0.w;
    acc[4] *= w1.x;  acc[5] *= w1.y;  acc[6] *= w1.z;  acc[7] *= w1.w;
    acc[8] *= w2.x;  acc[9] *= w2.y;  acc[10] *= w2.z; acc[11] *= w2.w;
    acc[12] *= w3.x; acc[13] *= w3.y; acc[14] *= w3.z; acc[15] *= w3.w;
  }

  bf16x8 a[2];
#pragma unroll
  for (int e = 0; e < 8; e++) {
    a[0][e] = (short)f2bf(acc[e]);
    a[1][e] = (short)f2bf(acc[8 + e]);
  }

  f32x4 acc2[4];
#pragma unroll
  for (int n = 0; n < 4; n++) {
    float bv = bo[n * 16 + r15];
    acc2[n] = (f32x4){bv, bv, bv, bv};
  }
#pragma unroll
  for (int s = 0; s < 2; s++) {
    const int koff = s * 32 + ck * 8;
#pragma unroll
    for (int n = 0; n < 4; n++) {
      bf16x8 bf = *(const bf16x8*)(wot + (n * 16 + r15) * KH + koff);
      acc2[n] = __builtin_amdgcn_mfma_f32_16x16x32_bf16(a[s], bf, acc2[n], 0, 0, 0);
    }
  }
#pragma unroll
  for (int n = 0; n < 4; n++) {
#pragma unroll
    for (int j = 0; j < 4; j++) {
      const int orow = base + ck * 4 + j;
      if (orow < nb) {
        const int d = n * 16 + r15;
        out[(long)orow * KD + d] = acc2[n][j] + bond[(long)orow * KD + d];
      }
    }
  }
}

extern "C" void kernel_launch(void* const* d_in, const int* in_sizes, int n_in,
                              void* d_out, int out_size, void* d_ws, size_t ws_size,
                              hipStream_t stream) {
  const float* atom = (const float*)d_in[0];
  const float* bond = (const float*)d_in[1];
  const float* bwt  = (const float*)d_in[2];
  const float* ang  = (const float*)d_in[3];
  const int*   bgr  = (const int*)d_in[4];
  const float* wc1 = (const float*)d_in[5];
  const float* bc1 = (const float*)d_in[6];
  const float* wc2 = (const float*)d_in[7];
  const float* bc2 = (const float*)d_in[8];
  const float* wg1 = (const float*)d_in[9];
  const float* bg1 = (const float*)d_in[10];
  const float* wg2 = (const float*)d_in[11];
  const float* bg2 = (const float*)d_in[12];
  const float* wo  = (const float*)d_in[13];
  const float* bo  = (const float*)d_in[14];

  const int na = in_sizes[0] / KD;   // atoms (40000); all bond_graph indices < na
  const int nb = in_sizes[1] / KD;   // bonds (200000)
  const int ng = in_sizes[4] / 3;    // angles (500000)
  float* out = (float*)d_out;

  char* pp = (char*)d_ws;
  auto alloc = [&](size_t bytes) { char* r = pp; pp += (bytes + 255) & ~(size_t)255; return r; };
  unsigned short* wpb  = (unsigned short*)alloc(16384 * 2);
  unsigned short* wpa  = (unsigned short*)alloc(8192 * 2);
  unsigned short* wpg  = (unsigned short*)alloc(8192 * 2);
  unsigned short* wc2t = (unsigned short*)alloc((size_t)KH * KD * 2);
  unsigned short* wg2t = (unsigned short*)alloc((size_t)KH * KD * 2);
  unsigned short* wot  = (unsigned short*)alloc((size_t)KH * KD * 2);
  float* biaspg        = (float*)alloc(128 * 4);
  unsigned char* PBX   = (unsigned char*)alloc((size_t)na * 384);       // 15.4 MB
  unsigned char* PA    = (unsigned char*)alloc((size_t)na * 128);       // 5.1 MB
  unsigned short* upd2 = (unsigned short*)alloc((size_t)ng * KD * 2);   // 64 MB
  int* cnt  = (int*)alloc((size_t)na * 4);
  int* cur  = (int*)alloc((size_t)na * 4);
  int* offb = (int*)alloc((size_t)na * 4);
  int* part = (int*)alloc((size_t)na * 4);
  int* bsum  = (int*)alloc(4096);
  int* bscan = (int*)alloc(4096);

  const int nblk = (na + 255) / 256;   // 157 <= 1024

  hipMemsetAsync(cnt, 0, (size_t)na * 4, stream);

  k_prep<<<(ng + 255) / 256, 256, 0, stream>>>(wc1, wg1, wc2, wg2, wo, bc1, bg1,
                                               wpb, wpa, wpg, wc2t, wg2t, wot, biaspg,
                                               bgr, cnt, ng);
  k_scan1<<<nblk, 256, 0, stream>>>(cnt, part, bsum, na);
  k_scan2<<<1, 1024, 0, stream>>>(bsum, bscan, nblk);
  k_scan3<<<nblk, 256, 0, stream>>>(part, bscan, offb, cur, na);

  const int tb = (na + 63) / 64;       // 625
  k_partial<256><<<tb, 256, 0, stream>>>(bond, wpb, PBX, na, 384, bwt);
  k_partial<128><<<tb, 256, 0, stream>>>(atom, wpa, PA, na, 128, (const float*)nullptr);

  k_fused<<<2048, 256, 0, stream>>>(ang, wpg, biaspg, bgr, offb, cur,
                                    PBX, PA, wc2t, wg2t, bc2, bg2, upd2, ng);

  k_aggout<<<(nb + 63) / 64, 256, 0, stream>>>(bond, bwt, upd2, offb, cnt,
                                               wot, bo, out, na, nb);
}

// Round 13
// 275.666 us; speedup vs baseline: 1.2363x; 1.1379x over previous
//
#include <hip/hip_runtime.h>
#include <hip/hip_bf16.h>

static constexpr int KD  = 64;
static constexpr int KH  = 64;

typedef __attribute__((ext_vector_type(8))) short bf16x8;
typedef __attribute__((ext_vector_type(4))) float f32x4;
typedef __attribute__((ext_vector_type(2))) float f32x2;

__device__ inline unsigned short f2bf(float f) {
  union { float f; unsigned u; } uf; uf.f = f;
  unsigned u = uf.u;
  return (unsigned short)((u + 0x7FFFu + ((u >> 16) & 1u)) >> 16);
}
__device__ inline float bf2f(unsigned short h) {
  union { unsigned u; float f; } x; x.u = ((unsigned)h) << 16; return x.f;
}
__device__ inline bf16x8 pack8(const float* p) {
  float4 lo = *(const float4*)p;
  float4 hi = *(const float4*)(p + 4);
  bf16x8 v;
  v[0] = (short)f2bf(lo.x); v[1] = (short)f2bf(lo.y);
  v[2] = (short)f2bf(lo.z); v[3] = (short)f2bf(lo.w);
  v[4] = (short)f2bf(hi.x); v[5] = (short)f2bf(hi.y);
  v[6] = (short)f2bf(hi.z); v[7] = (short)f2bf(hi.w);
  return v;
}
__device__ inline float sigm(float x) { return 1.0f / (1.0f + __expf(-x)); }
__device__ inline float silu_(float x) { return x * sigm(x); }
__device__ inline unsigned pk_fp8x4(float a0, float a1, float a2, float a3) {
  int v = __builtin_amdgcn_cvt_pk_fp8_f32(a0, a1, 0, false);
  v = __builtin_amdgcn_cvt_pk_fp8_f32(a2, a3, v, true);
  return (unsigned)v;
}
__device__ inline unsigned cvtpk_bf16(float lo, float hi) {
  unsigned r;
  asm("v_cvt_pk_bf16_f32 %0, %1, %2" : "=v"(r) : "v"(lo), "v"(hi));
  return r;
}
template<bool HI>
__device__ inline f32x2 sum3_fp8(unsigned a, unsigned b, unsigned c) {
  f32x2 A = __builtin_amdgcn_cvt_pk_f32_fp8((int)a, HI);
  f32x2 B = __builtin_amdgcn_cvt_pk_f32_fp8((int)b, HI);
  f32x2 C = __builtin_amdgcn_cvt_pk_f32_fp8((int)c, HI);
  return (A + B) + C;
}
// pair-permuted quad offset within a 64-value fp8 group: quad (n in 0..3, p)
__device__ inline int quad_off(int n, int p) {
  return ((n >> 1) << 5) + (p << 3) + ((n & 1) << 2);
}

// ---- K0: frag-major W1 tables + sigma-permuted W2 + natural Wo + biases + hist
__global__ void k_prep(const float* __restrict__ wc1, const float* __restrict__ wg1,
                       const float* __restrict__ wc2, const float* __restrict__ wg2,
                       const float* __restrict__ wo,
                       const float* __restrict__ bc1, const float* __restrict__ bg1,
                       unsigned short* __restrict__ wpb, unsigned short* __restrict__ wpa,
                       unsigned short* __restrict__ wpg,
                       unsigned short* __restrict__ wc2t, unsigned short* __restrict__ wg2t,
                       unsigned short* __restrict__ wot, float* __restrict__ biaspg,
                       const int* __restrict__ bgr, int* __restrict__ cnt, int ng) {
  int t = blockIdx.x * 256 + threadIdx.x;
  if (t < 16384) {          // wpb: NOUT=256 (bond slots 1+2, core+gate)
    int blk = t >> 9, n = blk >> 1, s = blk & 1;
    int lane = (t >> 3) & 63, e = t & 7;
    int p = lane >> 4, q = lane & 15;
    int k = 32 * s + 8 * p + e;
    int o = 16 * n + q;
    float v;
    if (o < 64)       v = wc1[k * KH + o];
    else if (o < 128) v = wg1[k * KH + (o - 64)];
    else if (o < 192) v = wc1[(64 + k) * KH + (o - 128)];
    else              v = wg1[(64 + k) * KH + (o - 192)];
    wpb[t] = f2bf(v);
  }
  if (t < 8192) {           // wpa / wpg: NOUT=128 (atom rows 192:256, angle rows 128:192)
    int blk = t >> 9, n = blk >> 1, s = blk & 1;
    int lane = (t >> 3) & 63, e = t & 7;
    int p = lane >> 4, q = lane & 15;
    int k = 32 * s + 8 * p + e;
    int o = 16 * n + q;
    float va = (o < 64) ? wc1[(192 + k) * KH + o] : wg1[(192 + k) * KH + (o - 64)];
    wpa[t] = f2bf(va);
    float vg = (o < 64) ? wc1[(128 + k) * KH + o] : wg1[(128 + k) * KH + (o - 64)];
    wpg[t] = f2bf(vg);
  }
  if (t < KH * KD) {
    int d = t >> 6, kp = t & 63;
    int h = 32 * (kp >> 5) + 16 * ((kp >> 2) & 1) + 4 * ((kp >> 3) & 3) + (kp & 3);
    wc2t[t] = f2bf(wc2[h * KD + d]);   // sigma-permuted [d][k']
    wg2t[t] = f2bf(wg2[h * KD + d]);
    wot[t]  = f2bf(wo[kp * KD + d]);   // natural [d][k]
  }
  if (t < 128) biaspg[t] = (t < 64) ? bc1[t] : bg1[t - 64];
  if (t < ng) atomicAdd(&cnt[bgr[3 * t + 1]], 1);
}

// ---- passA (bond/atom): P[r] = X[r] @ Wseg, fp8 out, PAIR-PERMUTED quads -----
template<int NOUT>
__global__ __launch_bounds__(256) void k_partial(
    const float* __restrict__ X, const unsigned short* __restrict__ wfrag,
    unsigned char* __restrict__ P, int nrows,
    int rowstride, const float* __restrict__ bwsrc) {
  constexpr int NSH = NOUT * 64;
  __shared__ unsigned short wl[NSH];
  const int tid = threadIdx.x;
  for (int c = tid * 8; c < NSH; c += 256 * 8)
    *(bf16x8*)&wl[c] = *(const bf16x8*)&wfrag[c];
  __syncthreads();
  const int wave = tid >> 6, lane = tid & 63, p = lane >> 4, q = lane & 15;
  const int ntile = (nrows + 63) >> 6;
  for (int tile = blockIdx.x; tile < ntile; tile += gridDim.x) {
    const int r0 = tile * 64 + wave * 16 + q;
    const int r = (r0 < nrows) ? r0 : (nrows - 1);
    bf16x8 b[2];
    b[0] = pack8(X + (long)r * 64 + 8 * p);
    b[1] = pack8(X + (long)r * 64 + 32 + 8 * p);
    unsigned char* dst = P + (long)r0 * rowstride;
#pragma unroll
    for (int n = 0; n < NOUT / 16; n++) {
      f32x4 acc = (f32x4){0.f, 0.f, 0.f, 0.f};
#pragma unroll
      for (int s = 0; s < 2; s++) {
        bf16x8 a = *(const bf16x8*)&wl[((n * 2 + s) * 64 + lane) * 8];
        acc = __builtin_amdgcn_mfma_f32_16x16x32_bf16(a, b[s], acc, 0, 0, 0);
      }
      if (r0 < nrows) {
        const int po = ((n >> 2) << 6) + quad_off(n & 3, p);
        *(unsigned*)(dst + po) = pk_fp8x4(acc[0], acc[1], acc[2], acc[3]);
      }
    }
    if (bwsrc != nullptr && r0 < nrows) {
#pragma unroll
      for (int n = 0; n < 4; n++) {
        float4 w = *(const float4*)(bwsrc + (long)r0 * 64 + 16 * n + 4 * p);
        *(unsigned*)(dst + 256 + quad_off(n, p)) = pk_fp8x4(w.x, w.y, w.z, w.w);
      }
    }
  }
}

// ---- scans -------------------------------------------------------------------
__global__ __launch_bounds__(256) void k_scan1(const int* __restrict__ cnt,
                                               int* __restrict__ part,
                                               int* __restrict__ bsum, int n) {
  __shared__ int wsum[4];
  const int tid = threadIdx.x;
  const int i = blockIdx.x * 256 + tid;
  const int lane = tid & 63, w = tid >> 6;
  int orig = (i < n) ? cnt[i] : 0;
  int v = orig;
#pragma unroll
  for (int d = 1; d < 64; d <<= 1) {
    int t = __shfl_up(v, d);
    if (lane >= d) v += t;
  }
  if (lane == 63) wsum[w] = v;
  __syncthreads();
  int add = 0;
  for (int k = 0; k < w; k++) add += wsum[k];
  v += add;
  if (i < n) part[i] = v - orig;
  if (tid == 255) bsum[blockIdx.x] = v;
}

__global__ __launch_bounds__(1024) void k_scan2(const int* __restrict__ bsum,
                                                int* __restrict__ bscan, int nblk) {
  __shared__ int wsum[16];
  const int tid = threadIdx.x;
  const int lane = tid & 63, w = tid >> 6;
  int orig = (tid < nblk) ? bsum[tid] : 0;
  int v = orig;
#pragma unroll
  for (int d = 1; d < 64; d <<= 1) {
    int t = __shfl_up(v, d);
    if (lane >= d) v += t;
  }
  if (lane == 63) wsum[w] = v;
  __syncthreads();
  int add = 0;
  for (int k = 0; k < w; k++) add += wsum[k];
  v += add;
  if (tid < nblk) bscan[tid] = v - orig;
}

__global__ void k_scan3(const int* __restrict__ part, const int* __restrict__ bscan,
                        int* __restrict__ off, int* __restrict__ cur, int n) {
  int i = blockIdx.x * blockDim.x + threadIdx.x;
  if (i < n) {
    off[i] = part[i] + bscan[i >> 8];
    cur[i] = 0;
  }
}

// ---- k_fused: sequential core/gate paths, pair-load gathers, bgr prefetch ----
__global__ __launch_bounds__(256) void k_fused(
    const float* __restrict__ ang, const unsigned short* __restrict__ wfrag,
    const float* __restrict__ biaspg, const int* __restrict__ bgr,
    const int* __restrict__ off, int* __restrict__ cur,
    const unsigned char* __restrict__ PBX, const unsigned char* __restrict__ PA,
    const unsigned short* __restrict__ wc2t, const unsigned short* __restrict__ wg2t,
    const float* __restrict__ bc2, const float* __restrict__ bg2,
    unsigned short* __restrict__ upd2, int ng) {
  __shared__ unsigned short wl[128 * 64];
  const int tid = threadIdx.x;
  for (int c = tid * 8; c < 128 * 64; c += 256 * 8)
    *(bf16x8*)&wl[c] = *(const bf16x8*)&wfrag[c];
  __syncthreads();
  const int wave = tid >> 6, lane = tid & 63, p = lane >> 4, q = lane & 15;
  const int ntile = (ng + 63) >> 6;
  const int p8 = p << 3;

  int tile = blockIdx.x;
  int ci, bi, bj;
  {
    const int g0 = tile * 64 + wave * 16 + q;
    const int g = (g0 < ng) ? g0 : (ng - 1);
    ci = bgr[3 * g]; bi = bgr[3 * g + 1]; bj = bgr[3 * g + 2];
  }
  for (; tile < ntile; tile += gridDim.x) {
    const int g0 = tile * 64 + wave * 16 + q;
    const bool ok = g0 < ng;
    const int g = ok ? g0 : (ng - 1);

    // prefetch next tile indices (removes a round-trip from the next iter's chain)
    int nci = ci, nbi = bi, nbj = bj;
    const int tnext = tile + gridDim.x;
    if (tnext < ntile) {
      const int g0n = tnext * 64 + wave * 16 + q;
      const int gn = (g0n < ng) ? g0n : (ng - 1);
      nci = bgr[3 * gn]; nbi = bgr[3 * gn + 1]; nbj = bgr[3 * gn + 2];
    }

    // rank via CSR cursor
    int rr = 0;
    if (p == 0 && ok) {
      int slot = atomicAdd(&cur[bi], 1);
      rr = off[bi] + slot;
    }
    rr = __shfl(rr, q);

    const unsigned char* rb1 = PBX + (long)bi * 384;        // c1 @0, g1 @64
    const unsigned char* rb2 = PBX + (long)bj * 384 + 128;  // c2 @0, g2 @64, bw @128
    const unsigned char* ra  = PA + (long)ci * 128;         // c @0, g @64

    // ---- CORE path -----------------------------------------------------
    uint2 c1[2], c2[2], c3[2];
#pragma unroll
    for (int np = 0; np < 2; np++) {
      const int o = (np << 5) + p8;
      c1[np] = *(const uint2*)(rb1 + o);
      c2[np] = *(const uint2*)(rb2 + o);
      c3[np] = *(const uint2*)(ra + o);
    }
    bf16x8 b0 = pack8(ang + (long)g * 64 + p8);
    bf16x8 b1 = pack8(ang + (long)g * 64 + 32 + p8);

    f32x4 h[4];
#pragma unroll
    for (int n = 0; n < 4; n++)
      h[n] = (f32x4&)*(const float4*)(biaspg + 16 * n + 4 * p);
#pragma unroll
    for (int n = 0; n < 4; n++) {
      bf16x8 a0 = *(const bf16x8*)&wl[((n * 2 + 0) * 64 + lane) * 8];
      h[n] = __builtin_amdgcn_mfma_f32_16x16x32_bf16(a0, b0, h[n], 0, 0, 0);
      bf16x8 a1 = *(const bf16x8*)&wl[((n * 2 + 1) * 64 + lane) * 8];
      h[n] = __builtin_amdgcn_mfma_f32_16x16x32_bf16(a1, b1, h[n], 0, 0, 0);
    }
#pragma unroll
    for (int np = 0; np < 2; np++) {
      f32x2 lo = sum3_fp8<false>(c1[np].x, c2[np].x, c3[np].x);
      f32x2 hi = sum3_fp8<true >(c1[np].x, c2[np].x, c3[np].x);
      h[2*np][0] += lo[0]; h[2*np][1] += lo[1]; h[2*np][2] += hi[0]; h[2*np][3] += hi[1];
      lo = sum3_fp8<false>(c1[np].y, c2[np].y, c3[np].y);
      hi = sum3_fp8<true >(c1[np].y, c2[np].y, c3[np].y);
      h[2*np+1][0] += lo[0]; h[2*np+1][1] += lo[1]; h[2*np+1][2] += hi[0]; h[2*np+1][3] += hi[1];
    }
    bf16x8 b2f[2];
#pragma unroll
    for (int s2 = 0; s2 < 2; s2++) {
      union { unsigned u[4]; bf16x8 v; } t;
#pragma unroll
      for (int eh = 0; eh < 4; eh++) {
        const int e0 = 2 * eh;
        const int n = 2 * s2 + (e0 >> 2), j = e0 & 3;
        t.u[eh] = cvtpk_bf16(silu_(h[n][j]), silu_(h[n][j + 1]));
      }
      b2f[s2] = t.v;
    }

    // issue GATE gathers + bw now (fly under GEMM2-c)
    uint2 g1[2], g2[2], g3[2], bwp[2];
#pragma unroll
    for (int np = 0; np < 2; np++) {
      const int o = 64 + (np << 5) + p8;
      g1[np] = *(const uint2*)(rb1 + o);
      g2[np] = *(const uint2*)(rb2 + o);
      g3[np] = *(const uint2*)(ra + o);
      bwp[np] = *(const uint2*)(rb2 + 128 + (np << 5) + p8);
    }

    // GEMM2-core -> silu(oc) saved
    f32x4 o4[4];
#pragma unroll
    for (int n2 = 0; n2 < 4; n2++)
      o4[n2] = (f32x4&)*(const float4*)(bc2 + 16 * n2 + 4 * p);
#pragma unroll
    for (int s2 = 0; s2 < 2; s2++) {
      const int ko = 32 * s2 + p8;
#pragma unroll
      for (int n2 = 0; n2 < 4; n2++) {
        bf16x8 a1 = *(const bf16x8*)(wc2t + (q + 16 * n2) * KH + ko);
        o4[n2] = __builtin_amdgcn_mfma_f32_16x16x32_bf16(a1, b2f[s2], o4[n2], 0, 0, 0);
      }
    }
    float sc[16];
#pragma unroll
    for (int n2 = 0; n2 < 4; n2++)
#pragma unroll
      for (int j = 0; j < 4; j++)
        sc[4 * n2 + j] = silu_(o4[n2][j]);

    // ---- GATE path (reuses h, o4) ---------------------------------------
#pragma unroll
    for (int n = 0; n < 4; n++)
      h[n] = (f32x4&)*(const float4*)(biaspg + 64 + 16 * n + 4 * p);
#pragma unroll
    for (int n = 0; n < 4; n++) {
      bf16x8 a0 = *(const bf16x8*)&wl[(((4 + n) * 2 + 0) * 64 + lane) * 8];
      h[n] = __builtin_amdgcn_mfma_f32_16x16x32_bf16(a0, b0, h[n], 0, 0, 0);
      bf16x8 a1 = *(const bf16x8*)&wl[(((4 + n) * 2 + 1) * 64 + lane) * 8];
      h[n] = __builtin_amdgcn_mfma_f32_16x16x32_bf16(a1, b1, h[n], 0, 0, 0);
    }
#pragma unroll
    for (int np = 0; np < 2; np++) {
      f32x2 lo = sum3_fp8<false>(g1[np].x, g2[np].x, g3[np].x);
      f32x2 hi = sum3_fp8<true >(g1[np].x, g2[np].x, g3[np].x);
      h[2*np][0] += lo[0]; h[2*np][1] += lo[1]; h[2*np][2] += hi[0]; h[2*np][3] += hi[1];
      lo = sum3_fp8<false>(g1[np].y, g2[np].y, g3[np].y);
      hi = sum3_fp8<true >(g1[np].y, g2[np].y, g3[np].y);
      h[2*np+1][0] += lo[0]; h[2*np+1][1] += lo[1]; h[2*np+1][2] += hi[0]; h[2*np+1][3] += hi[1];
    }
#pragma unroll
    for (int s2 = 0; s2 < 2; s2++) {
      union { unsigned u[4]; bf16x8 v; } t;
#pragma unroll
      for (int eh = 0; eh < 4; eh++) {
        const int e0 = 2 * eh;
        const int n = 2 * s2 + (e0 >> 2), j = e0 & 3;
        t.u[eh] = cvtpk_bf16(silu_(h[n][j]), silu_(h[n][j + 1]));
      }
      b2f[s2] = t.v;
    }
    f32x4 og[4];
#pragma unroll
    for (int n2 = 0; n2 < 4; n2++)
      og[n2] = (f32x4&)*(const float4*)(bg2 + 16 * n2 + 4 * p);
#pragma unroll
    for (int s2 = 0; s2 < 2; s2++) {
      const int ko = 32 * s2 + p8;
#pragma unroll
      for (int n2 = 0; n2 < 4; n2++) {
        bf16x8 a2 = *(const bf16x8*)(wg2t + (q + 16 * n2) * KH + ko);
        og[n2] = __builtin_amdgcn_mfma_f32_16x16x32_bf16(a2, b2f[s2], og[n2], 0, 0, 0);
      }
    }

    // epilogue: upd2[rank][d] = silu(oc)*sigm(og)*bw_fp8[bj][d]
    if (ok) {
      unsigned short* dst = upd2 + (long)rr * KD;
#pragma unroll
      for (int n2 = 0; n2 < 4; n2++) {
        const unsigned w = (n2 & 1) ? bwp[n2 >> 1].y : bwp[n2 >> 1].x;
        f32x2 blo = __builtin_amdgcn_cvt_pk_f32_fp8((int)w, false);
        f32x2 bhi = __builtin_amdgcn_cvt_pk_f32_fp8((int)w, true);
        float f0 = sc[4 * n2 + 0] * sigm(og[n2][0]) * blo[0];
        float f1 = sc[4 * n2 + 1] * sigm(og[n2][1]) * blo[1];
        float f2 = sc[4 * n2 + 2] * sigm(og[n2][2]) * bhi[0];
        float f3 = sc[4 * n2 + 3] * sigm(og[n2][3]) * bhi[1];
        uint2 st;
        st.x = cvtpk_bf16(f0, f1);
        st.y = cvtpk_bf16(f2, f3);
        *(uint2*)(dst + 16 * n2 + 4 * p) = st;
      }
    }
    ci = nci; bi = nbi; bj = nbj;
  }
}

// ---- k_aggout: contiguous segment-sum(upd2)*bw[b] -> @Wo + bo + bond -> out ---
__global__ __launch_bounds__(256) void k_aggout(
    const float* __restrict__ bond, const float* __restrict__ bwt,
    const unsigned short* __restrict__ upd2,
    const int* __restrict__ off, const int* __restrict__ cnt,
    const unsigned short* __restrict__ wot, const float* __restrict__ bo,
    float* __restrict__ out, int na, int nb) {
  const int wave = threadIdx.x >> 6;
  const int lane = threadIdx.x & 63;
  const int r15 = lane & 15;
  const int ck = lane >> 4;
  const int base = blockIdx.x * 64 + wave * 16;
  const int b = base + r15;
  const bool hasseg = (b < na);
  const int bc = hasseg ? b : 0;
  const int o = off[bc];
  const int c = hasseg ? cnt[bc] : 0;
  const int d0 = ck * 8;

  float acc[16];
#pragma unroll
  for (int e = 0; e < 16; e++) acc[e] = 0.0f;

  int it = 0;
  for (; it + 2 <= c; it += 2) {
    const unsigned short* r0 = upd2 + (long)(o + it) * KD;
    const unsigned short* r1 = r0 + KD;
    bf16x8 l0 = *(const bf16x8*)(r0 + d0);
    bf16x8 h0 = *(const bf16x8*)(r0 + 32 + d0);
    bf16x8 l1 = *(const bf16x8*)(r1 + d0);
    bf16x8 h1 = *(const bf16x8*)(r1 + 32 + d0);
#pragma unroll
    for (int e = 0; e < 8; e++) {
      acc[e]     += bf2f((unsigned short)l0[e]) + bf2f((unsigned short)l1[e]);
      acc[8 + e] += bf2f((unsigned short)h0[e]) + bf2f((unsigned short)h1[e]);
    }
  }
  if (it < c) {
    const unsigned short* r0 = upd2 + (long)(o + it) * KD;
    bf16x8 l0 = *(const bf16x8*)(r0 + d0);
    bf16x8 h0 = *(const bf16x8*)(r0 + 32 + d0);
#pragma unroll
    for (int e = 0; e < 8; e++) {
      acc[e]     += bf2f((unsigned short)l0[e]);
      acc[8 + e] += bf2f((unsigned short)h0[e]);
    }
  }

  if (hasseg) {
    const float* w = bwt + (long)b * KD;
    float4 w0 = *(const float4*)(w + d0);
    float4 w1 = *(const float4*)(w + d0 + 4);
    float4 w2 = *(const float4*)(w + 32 + d0);
    float4 w3 = *(const float4*)(w + 32 + d0 + 4);
    acc[0] *= w0.x;  acc[1] *= w0.y;  acc[2] *= w0.z;  acc[3] *= w0.w;
    acc[4] *= w1.x;  acc[5] *= w1.y;  acc[6] *= w1.z;  acc[7] *= w1.w;
    acc[8] *= w2.x;  acc[9] *= w2.y;  acc[10] *= w2.z; acc[11] *= w2.w;
    acc[12] *= w3.x; acc[13] *= w3.y; acc[14] *= w3.z; acc[15] *= w3.w;
  }

  bf16x8 a[2];
#pragma unroll
  for (int e = 0; e < 8; e++) {
    a[0][e] = (short)f2bf(acc[e]);
    a[1][e] = (short)f2bf(acc[8 + e]);
  }

  f32x4 acc2[4];
#pragma unroll
  for (int n = 0; n < 4; n++) {
    float bv = bo[n * 16 + r15];
    acc2[n] = (f32x4){bv, bv, bv, bv};
  }
#pragma unroll
  for (int s = 0; s < 2; s++) {
    const int koff = s * 32 + ck * 8;
#pragma unroll
    for (int n = 0; n < 4; n++) {
      bf16x8 bf = *(const bf16x8*)(wot + (n * 16 + r15) * KH + koff);
      acc2[n] = __builtin_amdgcn_mfma_f32_16x16x32_bf16(a[s], bf, acc2[n], 0, 0, 0);
    }
  }
#pragma unroll
  for (int n = 0; n < 4; n++) {
#pragma unroll
    for (int j = 0; j < 4; j++) {
      const int orow = base + ck * 4 + j;
      if (orow < nb) {
        const int d = n * 16 + r15;
        out[(long)orow * KD + d] = acc2[n][j] + bond[(long)orow * KD + d];
      }
    }
  }
}

extern "C" void kernel_launch(void* const* d_in, const int* in_sizes, int n_in,
                              void* d_out, int out_size, void* d_ws, size_t ws_size,
                              hipStream_t stream) {
  const float* atom = (const float*)d_in[0];
  const float* bond = (const float*)d_in[1];
  const float* bwt  = (const float*)d_in[2];
  const float* ang  = (const float*)d_in[3];
  const int*   bgr  = (const int*)d_in[4];
  const float* wc1 = (const float*)d_in[5];
  const float* bc1 = (const float*)d_in[6];
  const float* wc2 = (const float*)d_in[7];
  const float* bc2 = (const float*)d_in[8];
  const float* wg1 = (const float*)d_in[9];
  const float* bg1 = (const float*)d_in[10];
  const float* wg2 = (const float*)d_in[11];
  const float* bg2 = (const float*)d_in[12];
  const float* wo  = (const float*)d_in[13];
  const float* bo  = (const float*)d_in[14];

  const int na = in_sizes[0] / KD;   // atoms (40000); all bond_graph indices < na
  const int nb = in_sizes[1] / KD;   // bonds (200000)
  const int ng = in_sizes[4] / 3;    // angles (500000)
  float* out = (float*)d_out;

  char* pp = (char*)d_ws;
  auto alloc = [&](size_t bytes) { char* r = pp; pp += (bytes + 255) & ~(size_t)255; return r; };
  unsigned short* wpb  = (unsigned short*)alloc(16384 * 2);
  unsigned short* wpa  = (unsigned short*)alloc(8192 * 2);
  unsigned short* wpg  = (unsigned short*)alloc(8192 * 2);
  unsigned short* wc2t = (unsigned short*)alloc((size_t)KH * KD * 2);
  unsigned short* wg2t = (unsigned short*)alloc((size_t)KH * KD * 2);
  unsigned short* wot  = (unsigned short*)alloc((size_t)KH * KD * 2);
  float* biaspg        = (float*)alloc(128 * 4);
  unsigned char* PBX   = (unsigned char*)alloc((size_t)na * 384);       // 15.4 MB
  unsigned char* PA    = (unsigned char*)alloc((size_t)na * 128);       // 5.1 MB
  unsigned short* upd2 = (unsigned short*)alloc((size_t)ng * KD * 2);   // 64 MB
  int* cnt  = (int*)alloc((size_t)na * 4);
  int* cur  = (int*)alloc((size_t)na * 4);
  int* offb = (int*)alloc((size_t)na * 4);
  int* part = (int*)alloc((size_t)na * 4);
  int* bsum  = (int*)alloc(4096);
  int* bscan = (int*)alloc(4096);

  const int nblk = (na + 255) / 256;   // 157 <= 1024

  hipMemsetAsync(cnt, 0, (size_t)na * 4, stream);

  k_prep<<<(ng + 255) / 256, 256, 0, stream>>>(wc1, wg1, wc2, wg2, wo, bc1, bg1,
                                               wpb, wpa, wpg, wc2t, wg2t, wot, biaspg,
                                               bgr, cnt, ng);
  k_scan1<<<nblk, 256, 0, stream>>>(cnt, part, bsum, na);
  k_scan2<<<1, 1024, 0, stream>>>(bsum, bscan, nblk);
  k_scan3<<<nblk, 256, 0, stream>>>(part, bscan, offb, cur, na);

  const int tb = (na + 63) / 64;       // 625
  k_partial<256><<<tb, 256, 0, stream>>>(bond, wpb, PBX, na, 384, bwt);
  k_partial<128><<<tb, 256, 0, stream>>>(atom, wpa, PA, na, 128, (const float*)nullptr);

  k_fused<<<2048, 256, 0, stream>>>(ang, wpg, biaspg, bgr, offb, cur,
                                    PBX, PA, wc2t, wg2t, bc2, bg2, upd2, ng);

  k_aggout<<<(nb + 63) / 64, 256, 0, stream>>>(bond, bwt, upd2, offb, cnt,
                                               wot, bo, out, na, nb);
}

// Round 14
// 269.989 us; speedup vs baseline: 1.2622x; 1.0210x over previous
//
#include <hip/hip_runtime.h>
#include <hip/hip_bf16.h>

static constexpr int KD  = 64;
static constexpr int KH  = 64;

typedef __attribute__((ext_vector_type(8))) short bf16x8;
typedef __attribute__((ext_vector_type(4))) float f32x4;
typedef __attribute__((ext_vector_type(2))) float f32x2;

__device__ inline unsigned short f2bf(float f) {
  union { float f; unsigned u; } uf; uf.f = f;
  unsigned u = uf.u;
  return (unsigned short)((u + 0x7FFFu + ((u >> 16) & 1u)) >> 16);
}
__device__ inline float bf2f(unsigned short h) {
  union { unsigned u; float f; } x; x.u = ((unsigned)h) << 16; return x.f;
}
// HW packed bf16 convert: 1 inst for 2 values (RNE, matches f2bf)
__device__ inline unsigned cvtpk_bf16(float lo, float hi) {
  unsigned r;
  asm("v_cvt_pk_bf16_f32 %0, %1, %2" : "=v"(r) : "v"(lo), "v"(hi));
  return r;
}
__device__ inline bf16x8 pack8(const float* p) {
  float4 lo = *(const float4*)p;
  float4 hi = *(const float4*)(p + 4);
  union { unsigned u[4]; bf16x8 v; } t;
  t.u[0] = cvtpk_bf16(lo.x, lo.y);
  t.u[1] = cvtpk_bf16(lo.z, lo.w);
  t.u[2] = cvtpk_bf16(hi.x, hi.y);
  t.u[3] = cvtpk_bf16(hi.z, hi.w);
  return t.v;
}
// rcp-based activations: v_rcp_f32 (~1 ULP) instead of full-precision divide seq
__device__ inline float sigm(float x) {
  return __builtin_amdgcn_rcpf(1.0f + __expf(-x));
}
__device__ inline float silu_(float x) { return x * sigm(x); }
__device__ inline unsigned pk_fp8x4(float a0, float a1, float a2, float a3) {
  int v = __builtin_amdgcn_cvt_pk_fp8_f32(a0, a1, 0, false);
  v = __builtin_amdgcn_cvt_pk_fp8_f32(a2, a3, v, true);
  return (unsigned)v;
}
template<bool HI>
__device__ inline f32x2 sum3_fp8(unsigned a, unsigned b, unsigned c) {
  f32x2 A = __builtin_amdgcn_cvt_pk_f32_fp8((int)a, HI);
  f32x2 B = __builtin_amdgcn_cvt_pk_f32_fp8((int)b, HI);
  f32x2 C = __builtin_amdgcn_cvt_pk_f32_fp8((int)c, HI);
  return (A + B) + C;
}
// pair-permuted quad offset within a 64-value fp8 group: quad (n in 0..3, p)
__device__ inline int quad_off(int n, int p) {
  return ((n >> 1) << 5) + (p << 3) + ((n & 1) << 2);
}

// ---- K0: frag-major W1 tables + sigma-permuted W2 + natural Wo + biases + hist
__global__ void k_prep(const float* __restrict__ wc1, const float* __restrict__ wg1,
                       const float* __restrict__ wc2, const float* __restrict__ wg2,
                       const float* __restrict__ wo,
                       const float* __restrict__ bc1, const float* __restrict__ bg1,
                       unsigned short* __restrict__ wpb, unsigned short* __restrict__ wpa,
                       unsigned short* __restrict__ wpg,
                       unsigned short* __restrict__ wc2t, unsigned short* __restrict__ wg2t,
                       unsigned short* __restrict__ wot, float* __restrict__ biaspg,
                       const int* __restrict__ bgr, int* __restrict__ cnt, int ng) {
  int t = blockIdx.x * 256 + threadIdx.x;
  if (t < 16384) {          // wpb: NOUT=256 (bond slots 1+2, core+gate)
    int blk = t >> 9, n = blk >> 1, s = blk & 1;
    int lane = (t >> 3) & 63, e = t & 7;
    int p = lane >> 4, q = lane & 15;
    int k = 32 * s + 8 * p + e;
    int o = 16 * n + q;
    float v;
    if (o < 64)       v = wc1[k * KH + o];
    else if (o < 128) v = wg1[k * KH + (o - 64)];
    else if (o < 192) v = wc1[(64 + k) * KH + (o - 128)];
    else              v = wg1[(64 + k) * KH + (o - 192)];
    wpb[t] = f2bf(v);
  }
  if (t < 8192) {           // wpa / wpg: NOUT=128 (atom rows 192:256, angle rows 128:192)
    int blk = t >> 9, n = blk >> 1, s = blk & 1;
    int lane = (t >> 3) & 63, e = t & 7;
    int p = lane >> 4, q = lane & 15;
    int k = 32 * s + 8 * p + e;
    int o = 16 * n + q;
    float va = (o < 64) ? wc1[(192 + k) * KH + o] : wg1[(192 + k) * KH + (o - 64)];
    wpa[t] = f2bf(va);
    float vg = (o < 64) ? wc1[(128 + k) * KH + o] : wg1[(128 + k) * KH + (o - 64)];
    wpg[t] = f2bf(vg);
  }
  if (t < KH * KD) {
    int d = t >> 6, kp = t & 63;
    int h = 32 * (kp >> 5) + 16 * ((kp >> 2) & 1) + 4 * ((kp >> 3) & 3) + (kp & 3);
    wc2t[t] = f2bf(wc2[h * KD + d]);   // sigma-permuted [d][k']
    wg2t[t] = f2bf(wg2[h * KD + d]);
    wot[t]  = f2bf(wo[kp * KD + d]);   // natural [d][k]
  }
  if (t < 128) biaspg[t] = (t < 64) ? bc1[t] : bg1[t - 64];
  if (t < ng) atomicAdd(&cnt[bgr[3 * t + 1]], 1);
}

// ---- passA (bond/atom): P[r] = X[r] @ Wseg, fp8 out, PAIR-PERMUTED quads -----
template<int NOUT>
__global__ __launch_bounds__(256) void k_partial(
    const float* __restrict__ X, const unsigned short* __restrict__ wfrag,
    unsigned char* __restrict__ P, int nrows,
    int rowstride, const float* __restrict__ bwsrc) {
  constexpr int NSH = NOUT * 64;
  __shared__ unsigned short wl[NSH];
  const int tid = threadIdx.x;
  for (int c = tid * 8; c < NSH; c += 256 * 8)
    *(bf16x8*)&wl[c] = *(const bf16x8*)&wfrag[c];
  __syncthreads();
  const int wave = tid >> 6, lane = tid & 63, p = lane >> 4, q = lane & 15;
  const int ntile = (nrows + 63) >> 6;
  for (int tile = blockIdx.x; tile < ntile; tile += gridDim.x) {
    const int r0 = tile * 64 + wave * 16 + q;
    const int r = (r0 < nrows) ? r0 : (nrows - 1);
    bf16x8 b[2];
    b[0] = pack8(X + (long)r * 64 + 8 * p);
    b[1] = pack8(X + (long)r * 64 + 32 + 8 * p);
    unsigned char* dst = P + (long)r0 * rowstride;
#pragma unroll
    for (int n = 0; n < NOUT / 16; n++) {
      f32x4 acc = (f32x4){0.f, 0.f, 0.f, 0.f};
#pragma unroll
      for (int s = 0; s < 2; s++) {
        bf16x8 a = *(const bf16x8*)&wl[((n * 2 + s) * 64 + lane) * 8];
        acc = __builtin_amdgcn_mfma_f32_16x16x32_bf16(a, b[s], acc, 0, 0, 0);
      }
      if (r0 < nrows) {
        const int po = ((n >> 2) << 6) + quad_off(n & 3, p);
        *(unsigned*)(dst + po) = pk_fp8x4(acc[0], acc[1], acc[2], acc[3]);
      }
    }
    if (bwsrc != nullptr && r0 < nrows) {
#pragma unroll
      for (int n = 0; n < 4; n++) {
        float4 w = *(const float4*)(bwsrc + (long)r0 * 64 + 16 * n + 4 * p);
        *(unsigned*)(dst + 256 + quad_off(n, p)) = pk_fp8x4(w.x, w.y, w.z, w.w);
      }
    }
  }
}

// ---- scans -------------------------------------------------------------------
__global__ __launch_bounds__(256) void k_scan1(const int* __restrict__ cnt,
                                               int* __restrict__ part,
                                               int* __restrict__ bsum, int n) {
  __shared__ int wsum[4];
  const int tid = threadIdx.x;
  const int i = blockIdx.x * 256 + tid;
  const int lane = tid & 63, w = tid >> 6;
  int orig = (i < n) ? cnt[i] : 0;
  int v = orig;
#pragma unroll
  for (int d = 1; d < 64; d <<= 1) {
    int t = __shfl_up(v, d);
    if (lane >= d) v += t;
  }
  if (lane == 63) wsum[w] = v;
  __syncthreads();
  int add = 0;
  for (int k = 0; k < w; k++) add += wsum[k];
  v += add;
  if (i < n) part[i] = v - orig;
  if (tid == 255) bsum[blockIdx.x] = v;
}

__global__ __launch_bounds__(1024) void k_scan2(const int* __restrict__ bsum,
                                                int* __restrict__ bscan, int nblk) {
  __shared__ int wsum[16];
  const int tid = threadIdx.x;
  const int lane = tid & 63, w = tid >> 6;
  int orig = (tid < nblk) ? bsum[tid] : 0;
  int v = orig;
#pragma unroll
  for (int d = 1; d < 64; d <<= 1) {
    int t = __shfl_up(v, d);
    if (lane >= d) v += t;
  }
  if (lane == 63) wsum[w] = v;
  __syncthreads();
  int add = 0;
  for (int k = 0; k < w; k++) add += wsum[k];
  v += add;
  if (tid < nblk) bscan[tid] = v - orig;
}

__global__ void k_scan3(const int* __restrict__ part, const int* __restrict__ bscan,
                        int* __restrict__ off, int* __restrict__ cur, int n) {
  int i = blockIdx.x * blockDim.x + threadIdx.x;
  if (i < n) {
    off[i] = part[i] + bscan[i >> 8];
    cur[i] = 0;
  }
}

// ---- k_fused: sequential core/gate paths, pair-load gathers, bgr prefetch ----
__global__ __launch_bounds__(256) void k_fused(
    const float* __restrict__ ang, const unsigned short* __restrict__ wfrag,
    const float* __restrict__ biaspg, const int* __restrict__ bgr,
    const int* __restrict__ off, int* __restrict__ cur,
    const unsigned char* __restrict__ PBX, const unsigned char* __restrict__ PA,
    const unsigned short* __restrict__ wc2t, const unsigned short* __restrict__ wg2t,
    const float* __restrict__ bc2, const float* __restrict__ bg2,
    unsigned short* __restrict__ upd2, int ng) {
  __shared__ unsigned short wl[128 * 64];
  const int tid = threadIdx.x;
  for (int c = tid * 8; c < 128 * 64; c += 256 * 8)
    *(bf16x8*)&wl[c] = *(const bf16x8*)&wfrag[c];
  __syncthreads();
  const int wave = tid >> 6, lane = tid & 63, p = lane >> 4, q = lane & 15;
  const int ntile = (ng + 63) >> 6;
  const int p8 = p << 3;

  int tile = blockIdx.x;
  int ci, bi, bj;
  {
    const int g0 = tile * 64 + wave * 16 + q;
    const int g = (g0 < ng) ? g0 : (ng - 1);
    ci = bgr[3 * g]; bi = bgr[3 * g + 1]; bj = bgr[3 * g + 2];
  }
  for (; tile < ntile; tile += gridDim.x) {
    const int g0 = tile * 64 + wave * 16 + q;
    const bool ok = g0 < ng;
    const int g = ok ? g0 : (ng - 1);

    // prefetch next tile indices (removes a round-trip from the next iter's chain)
    int nci = ci, nbi = bi, nbj = bj;
    const int tnext = tile + gridDim.x;
    if (tnext < ntile) {
      const int g0n = tnext * 64 + wave * 16 + q;
      const int gn = (g0n < ng) ? g0n : (ng - 1);
      nci = bgr[3 * gn]; nbi = bgr[3 * gn + 1]; nbj = bgr[3 * gn + 2];
    }

    // rank via CSR cursor
    int rr = 0;
    if (p == 0 && ok) {
      int slot = atomicAdd(&cur[bi], 1);
      rr = off[bi] + slot;
    }
    rr = __shfl(rr, q);

    const unsigned char* rb1 = PBX + (long)bi * 384;        // c1 @0, g1 @64
    const unsigned char* rb2 = PBX + (long)bj * 384 + 128;  // c2 @0, g2 @64, bw @128
    const unsigned char* ra  = PA + (long)ci * 128;         // c @0, g @64

    // ---- CORE path -----------------------------------------------------
    uint2 c1[2], c2[2], c3[2];
#pragma unroll
    for (int np = 0; np < 2; np++) {
      const int o = (np << 5) + p8;
      c1[np] = *(const uint2*)(rb1 + o);
      c2[np] = *(const uint2*)(rb2 + o);
      c3[np] = *(const uint2*)(ra + o);
    }
    bf16x8 b0 = pack8(ang + (long)g * 64 + p8);
    bf16x8 b1 = pack8(ang + (long)g * 64 + 32 + p8);

    f32x4 h[4];
#pragma unroll
    for (int n = 0; n < 4; n++)
      h[n] = (f32x4&)*(const float4*)(biaspg + 16 * n + 4 * p);
#pragma unroll
    for (int n = 0; n < 4; n++) {
      bf16x8 a0 = *(const bf16x8*)&wl[((n * 2 + 0) * 64 + lane) * 8];
      h[n] = __builtin_amdgcn_mfma_f32_16x16x32_bf16(a0, b0, h[n], 0, 0, 0);
      bf16x8 a1 = *(const bf16x8*)&wl[((n * 2 + 1) * 64 + lane) * 8];
      h[n] = __builtin_amdgcn_mfma_f32_16x16x32_bf16(a1, b1, h[n], 0, 0, 0);
    }
#pragma unroll
    for (int np = 0; np < 2; np++) {
      f32x2 lo = sum3_fp8<false>(c1[np].x, c2[np].x, c3[np].x);
      f32x2 hi = sum3_fp8<true >(c1[np].x, c2[np].x, c3[np].x);
      h[2*np][0] += lo[0]; h[2*np][1] += lo[1]; h[2*np][2] += hi[0]; h[2*np][3] += hi[1];
      lo = sum3_fp8<false>(c1[np].y, c2[np].y, c3[np].y);
      hi = sum3_fp8<true >(c1[np].y, c2[np].y, c3[np].y);
      h[2*np+1][0] += lo[0]; h[2*np+1][1] += lo[1]; h[2*np+1][2] += hi[0]; h[2*np+1][3] += hi[1];
    }
    bf16x8 b2f[2];
#pragma unroll
    for (int s2 = 0; s2 < 2; s2++) {
      union { unsigned u[4]; bf16x8 v; } t;
#pragma unroll
      for (int eh = 0; eh < 4; eh++) {
        const int e0 = 2 * eh;
        const int n = 2 * s2 + (e0 >> 2), j = e0 & 3;
        t.u[eh] = cvtpk_bf16(silu_(h[n][j]), silu_(h[n][j + 1]));
      }
      b2f[s2] = t.v;
    }

    // issue GATE gathers + bw now (fly under GEMM2-c)
    uint2 g1[2], g2[2], g3[2], bwp[2];
#pragma unroll
    for (int np = 0; np < 2; np++) {
      const int o = 64 + (np << 5) + p8;
      g1[np] = *(const uint2*)(rb1 + o);
      g2[np] = *(const uint2*)(rb2 + o);
      g3[np] = *(const uint2*)(ra + o);
      bwp[np] = *(const uint2*)(rb2 + 128 + (np << 5) + p8);
    }

    // GEMM2-core -> silu(oc) saved
    f32x4 o4[4];
#pragma unroll
    for (int n2 = 0; n2 < 4; n2++)
      o4[n2] = (f32x4&)*(const float4*)(bc2 + 16 * n2 + 4 * p);
#pragma unroll
    for (int s2 = 0; s2 < 2; s2++) {
      const int ko = 32 * s2 + p8;
#pragma unroll
      for (int n2 = 0; n2 < 4; n2++) {
        bf16x8 a1 = *(const bf16x8*)(wc2t + (q + 16 * n2) * KH + ko);
        o4[n2] = __builtin_amdgcn_mfma_f32_16x16x32_bf16(a1, b2f[s2], o4[n2], 0, 0, 0);
      }
    }
    float sc[16];
#pragma unroll
    for (int n2 = 0; n2 < 4; n2++)
#pragma unroll
      for (int j = 0; j < 4; j++)
        sc[4 * n2 + j] = silu_(o4[n2][j]);

    // ---- GATE path (reuses h, o4) ---------------------------------------
#pragma unroll
    for (int n = 0; n < 4; n++)
      h[n] = (f32x4&)*(const float4*)(biaspg + 64 + 16 * n + 4 * p);
#pragma unroll
    for (int n = 0; n < 4; n++) {
      bf16x8 a0 = *(const bf16x8*)&wl[(((4 + n) * 2 + 0) * 64 + lane) * 8];
      h[n] = __builtin_amdgcn_mfma_f32_16x16x32_bf16(a0, b0, h[n], 0, 0, 0);
      bf16x8 a1 = *(const bf16x8*)&wl[(((4 + n) * 2 + 1) * 64 + lane) * 8];
      h[n] = __builtin_amdgcn_mfma_f32_16x16x32_bf16(a1, b1, h[n], 0, 0, 0);
    }
#pragma unroll
    for (int np = 0; np < 2; np++) {
      f32x2 lo = sum3_fp8<false>(g1[np].x, g2[np].x, g3[np].x);
      f32x2 hi = sum3_fp8<true >(g1[np].x, g2[np].x, g3[np].x);
      h[2*np][0] += lo[0]; h[2*np][1] += lo[1]; h[2*np][2] += hi[0]; h[2*np][3] += hi[1];
      lo = sum3_fp8<false>(g1[np].y, g2[np].y, g3[np].y);
      hi = sum3_fp8<true >(g1[np].y, g2[np].y, g3[np].y);
      h[2*np+1][0] += lo[0]; h[2*np+1][1] += lo[1]; h[2*np+1][2] += hi[0]; h[2*np+1][3] += hi[1];
    }
#pragma unroll
    for (int s2 = 0; s2 < 2; s2++) {
      union { unsigned u[4]; bf16x8 v; } t;
#pragma unroll
      for (int eh = 0; eh < 4; eh++) {
        const int e0 = 2 * eh;
        const int n = 2 * s2 + (e0 >> 2), j = e0 & 3;
        t.u[eh] = cvtpk_bf16(silu_(h[n][j]), silu_(h[n][j + 1]));
      }
      b2f[s2] = t.v;
    }
    f32x4 og[4];
#pragma unroll
    for (int n2 = 0; n2 < 4; n2++)
      og[n2] = (f32x4&)*(const float4*)(bg2 + 16 * n2 + 4 * p);
#pragma unroll
    for (int s2 = 0; s2 < 2; s2++) {
      const int ko = 32 * s2 + p8;
#pragma unroll
      for (int n2 = 0; n2 < 4; n2++) {
        bf16x8 a2 = *(const bf16x8*)(wg2t + (q + 16 * n2) * KH + ko);
        og[n2] = __builtin_amdgcn_mfma_f32_16x16x32_bf16(a2, b2f[s2], og[n2], 0, 0, 0);
      }
    }

    // epilogue: upd2[rank][d] = silu(oc)*sigm(og)*bw_fp8[bj][d]
    if (ok) {
      unsigned short* dst = upd2 + (long)rr * KD;
#pragma unroll
      for (int n2 = 0; n2 < 4; n2++) {
        const unsigned w = (n2 & 1) ? bwp[n2 >> 1].y : bwp[n2 >> 1].x;
        f32x2 blo = __builtin_amdgcn_cvt_pk_f32_fp8((int)w, false);
        f32x2 bhi = __builtin_amdgcn_cvt_pk_f32_fp8((int)w, true);
        float f0 = sc[4 * n2 + 0] * sigm(og[n2][0]) * blo[0];
        float f1 = sc[4 * n2 + 1] * sigm(og[n2][1]) * blo[1];
        float f2 = sc[4 * n2 + 2] * sigm(og[n2][2]) * bhi[0];
        float f3 = sc[4 * n2 + 3] * sigm(og[n2][3]) * bhi[1];
        uint2 st;
        st.x = cvtpk_bf16(f0, f1);
        st.y = cvtpk_bf16(f2, f3);
        *(uint2*)(dst + 16 * n2 + 4 * p) = st;
      }
    }
    ci = nci; bi = nbi; bj = nbj;
  }
}

// ---- k_aggout: contiguous segment-sum(upd2)*bw[b] -> @Wo + bo + bond -> out ---
__global__ __launch_bounds__(256) void k_aggout(
    const float* __restrict__ bond, const float* __restrict__ bwt,
    const unsigned short* __restrict__ upd2,
    const int* __restrict__ off, const int* __restrict__ cnt,
    const unsigned short* __restrict__ wot, const float* __restrict__ bo,
    float* __restrict__ out, int na, int nb) {
  const int wave = threadIdx.x >> 6;
  const int lane = threadIdx.x & 63;
  const int r15 = lane & 15;
  const int ck = lane >> 4;
  const int base = blockIdx.x * 64 + wave * 16;
  const int b = base + r15;
  const bool hasseg = (b < na);
  const int bc = hasseg ? b : 0;
  const int o = off[bc];
  const int c = hasseg ? cnt[bc] : 0;
  const int d0 = ck * 8;

  float acc[16];
#pragma unroll
  for (int e = 0; e < 16; e++) acc[e] = 0.0f;

  int it = 0;
  for (; it + 2 <= c; it += 2) {
    const unsigned short* r0 = upd2 + (long)(o + it) * KD;
    const unsigned short* r1 = r0 + KD;
    bf16x8 l0 = *(const bf16x8*)(r0 + d0);
    bf16x8 h0 = *(const bf16x8*)(r0 + 32 + d0);
    bf16x8 l1 = *(const bf16x8*)(r1 + d0);
    bf16x8 h1 = *(const bf16x8*)(r1 + 32 + d0);
#pragma unroll
    for (int e = 0; e < 8; e++) {
      acc[e]     += bf2f((unsigned short)l0[e]) + bf2f((unsigned short)l1[e]);
      acc[8 + e] += bf2f((unsigned short)h0[e]) + bf2f((unsigned short)h1[e]);
    }
  }
  if (it < c) {
    const unsigned short* r0 = upd2 + (long)(o + it) * KD;
    bf16x8 l0 = *(const bf16x8*)(r0 + d0);
    bf16x8 h0 = *(const bf16x8*)(r0 + 32 + d0);
#pragma unroll
    for (int e = 0; e < 8; e++) {
      acc[e]     += bf2f((unsigned short)l0[e]);
      acc[8 + e] += bf2f((unsigned short)h0[e]);
    }
  }

  if (hasseg) {
    const float* w = bwt + (long)b * KD;
    float4 w0 = *(const float4*)(w + d0);
    float4 w1 = *(const float4*)(w + d0 + 4);
    float4 w2 = *(const float4*)(w + 32 + d0);
    float4 w3 = *(const float4*)(w + 32 + d0 + 4);
    acc[0] *= w0.x;  acc[1] *= w0.y;  acc[2] *= w0.z;  acc[3] *= w0.w;
    acc[4] *= w1.x;  acc[5] *= w1.y;  acc[6] *= w1.z;  acc[7] *= w1.w;
    acc[8] *= w2.x;  acc[9] *= w2.y;  acc[10] *= w2.z; acc[11] *= w2.w;
    acc[12] *= w3.x; acc[13] *= w3.y; acc[14] *= w3.z; acc[15] *= w3.w;
  }

  bf16x8 a[2];
  {
    union { unsigned u[4]; bf16x8 v; } t0, t1;
    t0.u[0] = cvtpk_bf16(acc[0], acc[1]);
    t0.u[1] = cvtpk_bf16(acc[2], acc[3]);
    t0.u[2] = cvtpk_bf16(acc[4], acc[5]);
    t0.u[3] = cvtpk_bf16(acc[6], acc[7]);
    t1.u[0] = cvtpk_bf16(acc[8], acc[9]);
    t1.u[1] = cvtpk_bf16(acc[10], acc[11]);
    t1.u[2] = cvtpk_bf16(acc[12], acc[13]);
    t1.u[3] = cvtpk_bf16(acc[14], acc[15]);
    a[0] = t0.v;
    a[1] = t1.v;
  }

  f32x4 acc2[4];
#pragma unroll
  for (int n = 0; n < 4; n++) {
    float bv = bo[n * 16 + r15];
    acc2[n] = (f32x4){bv, bv, bv, bv};
  }
#pragma unroll
  for (int s = 0; s < 2; s++) {
    const int koff = s * 32 + ck * 8;
#pragma unroll
    for (int n = 0; n < 4; n++) {
      bf16x8 bf = *(const bf16x8*)(wot + (n * 16 + r15) * KH + koff);
      acc2[n] = __builtin_amdgcn_mfma_f32_16x16x32_bf16(a[s], bf, acc2[n], 0, 0, 0);
    }
  }
#pragma unroll
  for (int n = 0; n < 4; n++) {
#pragma unroll
    for (int j = 0; j < 4; j++) {
      const int orow = base + ck * 4 + j;
      if (orow < nb) {
        const int d = n * 16 + r15;
        out[(long)orow * KD + d] = acc2[n][j] + bond[(long)orow * KD + d];
      }
    }
  }
}

extern "C" void kernel_launch(void* const* d_in, const int* in_sizes, int n_in,
                              void* d_out, int out_size, void* d_ws, size_t ws_size,
                              hipStream_t stream) {
  const float* atom = (const float*)d_in[0];
  const float* bond = (const float*)d_in[1];
  const float* bwt  = (const float*)d_in[2];
  const float* ang  = (const float*)d_in[3];
  const int*   bgr  = (const int*)d_in[4];
  const float* wc1 = (const float*)d_in[5];
  const float* bc1 = (const float*)d_in[6];
  const float* wc2 = (const float*)d_in[7];
  const float* bc2 = (const float*)d_in[8];
  const float* wg1 = (const float*)d_in[9];
  const float* bg1 = (const float*)d_in[10];
  const float* wg2 = (const float*)d_in[11];
  const float* bg2 = (const float*)d_in[12];
  const float* wo  = (const float*)d_in[13];
  const float* bo  = (const float*)d_in[14];

  const int na = in_sizes[0] / KD;   // atoms (40000); all bond_graph indices < na
  const int nb = in_sizes[1] / KD;   // bonds (200000)
  const int ng = in_sizes[4] / 3;    // angles (500000)
  float* out = (float*)d_out;

  char* pp = (char*)d_ws;
  auto alloc = [&](size_t bytes) { char* r = pp; pp += (bytes + 255) & ~(size_t)255; return r; };
  unsigned short* wpb  = (unsigned short*)alloc(16384 * 2);
  unsigned short* wpa  = (unsigned short*)alloc(8192 * 2);
  unsigned short* wpg  = (unsigned short*)alloc(8192 * 2);
  unsigned short* wc2t = (unsigned short*)alloc((size_t)KH * KD * 2);
  unsigned short* wg2t = (unsigned short*)alloc((size_t)KH * KD * 2);
  unsigned short* wot  = (unsigned short*)alloc((size_t)KH * KD * 2);
  float* biaspg        = (float*)alloc(128 * 4);
  unsigned char* PBX   = (unsigned char*)alloc((size_t)na * 384);       // 15.4 MB
  unsigned char* PA    = (unsigned char*)alloc((size_t)na * 128);       // 5.1 MB
  unsigned short* upd2 = (unsigned short*)alloc((size_t)ng * KD * 2);   // 64 MB
  int* cnt  = (int*)alloc((size_t)na * 4);
  int* cur  = (int*)alloc((size_t)na * 4);
  int* offb = (int*)alloc((size_t)na * 4);
  int* part = (int*)alloc((size_t)na * 4);
  int* bsum  = (int*)alloc(4096);
  int* bscan = (int*)alloc(4096);

  const int nblk = (na + 255) / 256;   // 157 <= 1024

  hipMemsetAsync(cnt, 0, (size_t)na * 4, stream);

  k_prep<<<(ng + 255) / 256, 256, 0, stream>>>(wc1, wg1, wc2, wg2, wo, bc1, bg1,
                                               wpb, wpa, wpg, wc2t, wg2t, wot, biaspg,
                                               bgr, cnt, ng);
  k_scan1<<<nblk, 256, 0, stream>>>(cnt, part, bsum, na);
  k_scan2<<<1, 1024, 0, stream>>>(bsum, bscan, nblk);
  k_scan3<<<nblk, 256, 0, stream>>>(part, bscan, offb, cur, na);

  const int tb = (na + 63) / 64;       // 625
  k_partial<256><<<tb, 256, 0, stream>>>(bond, wpb, PBX, na, 384, bwt);
  k_partial<128><<<tb, 256, 0, stream>>>(atom, wpa, PA, na, 128, (const float*)nullptr);

  k_fused<<<2048, 256, 0, stream>>>(ang, wpg, biaspg, bgr, offb, cur,
                                    PBX, PA, wc2t, wg2t, bc2, bg2, upd2, ng);

  k_aggout<<<(nb + 63) / 64, 256, 0, stream>>>(bond, bwt, upd2, offb, cnt,
                                               wot, bo, out, na, nb);
}

// Round 15
// 248.878 us; speedup vs baseline: 1.3693x; 1.0848x over previous
//
#include <hip/hip_runtime.h>
#include <hip/hip_bf16.h>

static constexpr int KD  = 64;
static constexpr int KH  = 64;

typedef __attribute__((ext_vector_type(8))) short bf16x8;
typedef __attribute__((ext_vector_type(4))) float f32x4;
typedef __attribute__((ext_vector_type(2))) float f32x2;
typedef __attribute__((ext_vector_type(4))) unsigned u32x4;

__device__ inline unsigned short f2bf(float f) {
  union { float f; unsigned u; } uf; uf.f = f;
  unsigned u = uf.u;
  return (unsigned short)((u + 0x7FFFu + ((u >> 16) & 1u)) >> 16);
}
__device__ inline float bf2f(unsigned short h) {
  union { unsigned u; float f; } x; x.u = ((unsigned)h) << 16; return x.f;
}
// HW packed bf16 convert: 1 inst for 2 values (RNE)
__device__ inline unsigned cvtpk_bf16(float lo, float hi) {
  unsigned r;
  asm("v_cvt_pk_bf16_f32 %0, %1, %2" : "=v"(r) : "v"(lo), "v"(hi));
  return r;
}
__device__ inline bf16x8 pack8(const float* p) {
  float4 lo = *(const float4*)p;
  float4 hi = *(const float4*)(p + 4);
  union { unsigned u[4]; bf16x8 v; } t;
  t.u[0] = cvtpk_bf16(lo.x, lo.y);
  t.u[1] = cvtpk_bf16(lo.z, lo.w);
  t.u[2] = cvtpk_bf16(hi.x, hi.y);
  t.u[3] = cvtpk_bf16(hi.z, hi.w);
  return t.v;
}
// rcp-based activations (~1 ULP)
__device__ inline float sigm(float x) {
  return __builtin_amdgcn_rcpf(1.0f + __expf(-x));
}
__device__ inline float silu_(float x) { return x * sigm(x); }
__device__ inline unsigned pk_fp8x4(float a0, float a1, float a2, float a3) {
  int v = __builtin_amdgcn_cvt_pk_fp8_f32(a0, a1, 0, false);
  v = __builtin_amdgcn_cvt_pk_fp8_f32(a2, a3, v, true);
  return (unsigned)v;
}
template<bool HI>
__device__ inline f32x2 sum3_fp8(unsigned a, unsigned b, unsigned c) {
  f32x2 A = __builtin_amdgcn_cvt_pk_f32_fp8((int)a, HI);
  f32x2 B = __builtin_amdgcn_cvt_pk_f32_fp8((int)b, HI);
  f32x2 C = __builtin_amdgcn_cvt_pk_f32_fp8((int)c, HI);
  return (A + B) + C;
}
// p-major quad offset within a 64-value fp8 region: lane p owns [16p, 16p+16)
__device__ inline int quad_off(int n, int p) {
  return (p << 4) + (n << 2);
}

// ---- K0: frag-major W1 tables + sigma-permuted W2 + natural Wo + biases + hist
__global__ void k_prep(const float* __restrict__ wc1, const float* __restrict__ wg1,
                       const float* __restrict__ wc2, const float* __restrict__ wg2,
                       const float* __restrict__ wo,
                       const float* __restrict__ bc1, const float* __restrict__ bg1,
                       unsigned short* __restrict__ wpb, unsigned short* __restrict__ wpa,
                       unsigned short* __restrict__ wpg,
                       unsigned short* __restrict__ wc2t, unsigned short* __restrict__ wg2t,
                       unsigned short* __restrict__ wot, float* __restrict__ biaspg,
                       const int* __restrict__ bgr, int* __restrict__ cnt, int ng) {
  int t = blockIdx.x * 256 + threadIdx.x;
  if (t < 16384) {          // wpb: NOUT=256 (bond slots 1+2, core+gate)
    int blk = t >> 9, n = blk >> 1, s = blk & 1;
    int lane = (t >> 3) & 63, e = t & 7;
    int p = lane >> 4, q = lane & 15;
    int k = 32 * s + 8 * p + e;
    int o = 16 * n + q;
    float v;
    if (o < 64)       v = wc1[k * KH + o];
    else if (o < 128) v = wg1[k * KH + (o - 64)];
    else if (o < 192) v = wc1[(64 + k) * KH + (o - 128)];
    else              v = wg1[(64 + k) * KH + (o - 192)];
    wpb[t] = f2bf(v);
  }
  if (t < 8192) {           // wpa / wpg: NOUT=128 (atom rows 192:256, angle rows 128:192)
    int blk = t >> 9, n = blk >> 1, s = blk & 1;
    int lane = (t >> 3) & 63, e = t & 7;
    int p = lane >> 4, q = lane & 15;
    int k = 32 * s + 8 * p + e;
    int o = 16 * n + q;
    float va = (o < 64) ? wc1[(192 + k) * KH + o] : wg1[(192 + k) * KH + (o - 64)];
    wpa[t] = f2bf(va);
    float vg = (o < 64) ? wc1[(128 + k) * KH + o] : wg1[(128 + k) * KH + (o - 64)];
    wpg[t] = f2bf(vg);
  }
  if (t < KH * KD) {
    int d = t >> 6, kp = t & 63;
    int h = 32 * (kp >> 5) + 16 * ((kp >> 2) & 1) + 4 * ((kp >> 3) & 3) + (kp & 3);
    wc2t[t] = f2bf(wc2[h * KD + d]);   // sigma-permuted [d][k']
    wg2t[t] = f2bf(wg2[h * KD + d]);
    wot[t]  = f2bf(wo[kp * KD + d]);   // natural [d][k]
  }
  if (t < 128) biaspg[t] = (t < 64) ? bc1[t] : bg1[t - 64];
  if (t < ng) atomicAdd(&cnt[bgr[3 * t + 1]], 1);
}

// ---- passA (bond/atom): P[r] = X[r] @ Wseg, fp8 out, P-MAJOR quads -----------
template<int NOUT>
__global__ __launch_bounds__(256) void k_partial(
    const float* __restrict__ X, const unsigned short* __restrict__ wfrag,
    unsigned char* __restrict__ P, int nrows,
    int rowstride, const float* __restrict__ bwsrc) {
  constexpr int NSH = NOUT * 64;
  __shared__ unsigned short wl[NSH];
  const int tid = threadIdx.x;
  for (int c = tid * 8; c < NSH; c += 256 * 8)
    *(bf16x8*)&wl[c] = *(const bf16x8*)&wfrag[c];
  __syncthreads();
  const int wave = tid >> 6, lane = tid & 63, p = lane >> 4, q = lane & 15;
  const int ntile = (nrows + 63) >> 6;
  for (int tile = blockIdx.x; tile < ntile; tile += gridDim.x) {
    const int r0 = tile * 64 + wave * 16 + q;
    const int r = (r0 < nrows) ? r0 : (nrows - 1);
    bf16x8 b[2];
    b[0] = pack8(X + (long)r * 64 + 8 * p);
    b[1] = pack8(X + (long)r * 64 + 32 + 8 * p);
    unsigned char* dst = P + (long)r0 * rowstride;
#pragma unroll
    for (int n = 0; n < NOUT / 16; n++) {
      f32x4 acc = (f32x4){0.f, 0.f, 0.f, 0.f};
#pragma unroll
      for (int s = 0; s < 2; s++) {
        bf16x8 a = *(const bf16x8*)&wl[((n * 2 + s) * 64 + lane) * 8];
        acc = __builtin_amdgcn_mfma_f32_16x16x32_bf16(a, b[s], acc, 0, 0, 0);
      }
      if (r0 < nrows) {
        const int po = ((n >> 2) << 6) + quad_off(n & 3, p);
        *(unsigned*)(dst + po) = pk_fp8x4(acc[0], acc[1], acc[2], acc[3]);
      }
    }
    if (bwsrc != nullptr && r0 < nrows) {
#pragma unroll
      for (int n = 0; n < 4; n++) {
        float4 w = *(const float4*)(bwsrc + (long)r0 * 64 + 16 * n + 4 * p);
        *(unsigned*)(dst + 256 + quad_off(n, p)) = pk_fp8x4(w.x, w.y, w.z, w.w);
      }
    }
  }
}

// ---- scans -------------------------------------------------------------------
__global__ __launch_bounds__(256) void k_scan1(const int* __restrict__ cnt,
                                               int* __restrict__ part,
                                               int* __restrict__ bsum, int n) {
  __shared__ int wsum[4];
  const int tid = threadIdx.x;
  const int i = blockIdx.x * 256 + tid;
  const int lane = tid & 63, w = tid >> 6;
  int orig = (i < n) ? cnt[i] : 0;
  int v = orig;
#pragma unroll
  for (int d = 1; d < 64; d <<= 1) {
    int t = __shfl_up(v, d);
    if (lane >= d) v += t;
  }
  if (lane == 63) wsum[w] = v;
  __syncthreads();
  int add = 0;
  for (int k = 0; k < w; k++) add += wsum[k];
  v += add;
  if (i < n) part[i] = v - orig;
  if (tid == 255) bsum[blockIdx.x] = v;
}

__global__ __launch_bounds__(1024) void k_scan2(const int* __restrict__ bsum,
                                                int* __restrict__ bscan, int nblk) {
  __shared__ int wsum[16];
  const int tid = threadIdx.x;
  const int lane = tid & 63, w = tid >> 6;
  int orig = (tid < nblk) ? bsum[tid] : 0;
  int v = orig;
#pragma unroll
  for (int d = 1; d < 64; d <<= 1) {
    int t = __shfl_up(v, d);
    if (lane >= d) v += t;
  }
  if (lane == 63) wsum[w] = v;
  __syncthreads();
  int add = 0;
  for (int k = 0; k < w; k++) add += wsum[k];
  v += add;
  if (tid < nblk) bscan[tid] = v - orig;
}

__global__ void k_scan3(const int* __restrict__ part, const int* __restrict__ bscan,
                        int* __restrict__ off, int* __restrict__ cur, int n) {
  int i = blockIdx.x * blockDim.x + threadIdx.x;
  if (i < n) {
    off[i] = part[i] + bscan[i >> 8];
    cur[i] = 0;
  }
}

// ---- k_fused: ALL gathers upfront as uint4; sequential core/gate compute -----
__global__ __launch_bounds__(256) void k_fused(
    const float* __restrict__ ang, const unsigned short* __restrict__ wfrag,
    const float* __restrict__ biaspg, const int* __restrict__ bgr,
    const int* __restrict__ off, int* __restrict__ cur,
    const unsigned char* __restrict__ PBX, const unsigned char* __restrict__ PA,
    const unsigned short* __restrict__ wc2t, const unsigned short* __restrict__ wg2t,
    const float* __restrict__ bc2, const float* __restrict__ bg2,
    unsigned short* __restrict__ upd2, int ng) {
  __shared__ unsigned short wl[128 * 64];
  const int tid = threadIdx.x;
  for (int c = tid * 8; c < 128 * 64; c += 256 * 8)
    *(bf16x8*)&wl[c] = *(const bf16x8*)&wfrag[c];
  __syncthreads();
  const int wave = tid >> 6, lane = tid & 63, p = lane >> 4, q = lane & 15;
  const int ntile = (ng + 63) >> 6;
  const int p8 = p << 3;
  const int p16 = p << 4;

  int tile = blockIdx.x;
  int ci, bi, bj;
  {
    const int g0 = tile * 64 + wave * 16 + q;
    const int g = (g0 < ng) ? g0 : (ng - 1);
    ci = bgr[3 * g]; bi = bgr[3 * g + 1]; bj = bgr[3 * g + 2];
  }
  for (; tile < ntile; tile += gridDim.x) {
    const int g0 = tile * 64 + wave * 16 + q;
    const bool ok = g0 < ng;
    const int g = ok ? g0 : (ng - 1);

    const unsigned char* rb1 = PBX + (long)bi * 384;        // c1 @0, g1 @64
    const unsigned char* rb2 = PBX + (long)bj * 384 + 128;  // c2 @0, g2 @64, bw @128
    const unsigned char* ra  = PA + (long)ci * 128;         // c @0, g @64

    // ---- ALL scattered gathers issued upfront (7 uint4 loads, 4 lines) ----
    u32x4 c1 = *(const u32x4*)(rb1 + p16);
    u32x4 g1 = *(const u32x4*)(rb1 + 64 + p16);
    u32x4 c2 = *(const u32x4*)(rb2 + p16);
    u32x4 g2 = *(const u32x4*)(rb2 + 64 + p16);
    u32x4 ca = *(const u32x4*)(ra + p16);
    u32x4 ga = *(const u32x4*)(ra + 64 + p16);
    u32x4 bw = *(const u32x4*)(rb2 + 128 + p16);

    // dense ang loads
    bf16x8 b0 = pack8(ang + (long)g * 64 + p8);
    bf16x8 b1 = pack8(ang + (long)g * 64 + 32 + p8);

    // prefetch next tile indices
    int nci = ci, nbi = bi, nbj = bj;
    const int tnext = tile + gridDim.x;
    if (tnext < ntile) {
      const int g0n = tnext * 64 + wave * 16 + q;
      const int gn = (g0n < ng) ? g0n : (ng - 1);
      nci = bgr[3 * gn]; nbi = bgr[3 * gn + 1]; nbj = bgr[3 * gn + 2];
    }

    // rank via CSR cursor
    int rr = 0;
    if (p == 0 && ok) {
      int slot = atomicAdd(&cur[bi], 1);
      rr = off[bi] + slot;
    }
    rr = __shfl(rr, q);

    // ---- CORE path -----------------------------------------------------
    f32x4 h[4];
#pragma unroll
    for (int n = 0; n < 4; n++)
      h[n] = (f32x4&)*(const float4*)(biaspg + 16 * n + 4 * p);
#pragma unroll
    for (int n = 0; n < 4; n++) {
      bf16x8 a0 = *(const bf16x8*)&wl[((n * 2 + 0) * 64 + lane) * 8];
      h[n] = __builtin_amdgcn_mfma_f32_16x16x32_bf16(a0, b0, h[n], 0, 0, 0);
      bf16x8 a1 = *(const bf16x8*)&wl[((n * 2 + 1) * 64 + lane) * 8];
      h[n] = __builtin_amdgcn_mfma_f32_16x16x32_bf16(a1, b1, h[n], 0, 0, 0);
    }
#pragma unroll
    for (int n = 0; n < 4; n++) {
      f32x2 lo = sum3_fp8<false>(c1[n], c2[n], ca[n]);
      f32x2 hi = sum3_fp8<true >(c1[n], c2[n], ca[n]);
      h[n][0] += lo[0]; h[n][1] += lo[1]; h[n][2] += hi[0]; h[n][3] += hi[1];
    }
    bf16x8 b2f[2];
#pragma unroll
    for (int s2 = 0; s2 < 2; s2++) {
      union { unsigned u[4]; bf16x8 v; } t;
#pragma unroll
      for (int eh = 0; eh < 4; eh++) {
        const int e0 = 2 * eh;
        const int n = 2 * s2 + (e0 >> 2), j = e0 & 3;
        t.u[eh] = cvtpk_bf16(silu_(h[n][j]), silu_(h[n][j + 1]));
      }
      b2f[s2] = t.v;
    }

    // GEMM2-core -> silu(oc) saved
    f32x4 o4[4];
#pragma unroll
    for (int n2 = 0; n2 < 4; n2++)
      o4[n2] = (f32x4&)*(const float4*)(bc2 + 16 * n2 + 4 * p);
#pragma unroll
    for (int s2 = 0; s2 < 2; s2++) {
      const int ko = 32 * s2 + p8;
#pragma unroll
      for (int n2 = 0; n2 < 4; n2++) {
        bf16x8 a1 = *(const bf16x8*)(wc2t + (q + 16 * n2) * KH + ko);
        o4[n2] = __builtin_amdgcn_mfma_f32_16x16x32_bf16(a1, b2f[s2], o4[n2], 0, 0, 0);
      }
    }
    float sc[16];
#pragma unroll
    for (int n2 = 0; n2 < 4; n2++)
#pragma unroll
      for (int j = 0; j < 4; j++)
        sc[4 * n2 + j] = silu_(o4[n2][j]);

    // ---- GATE path (reuses h, o4) ---------------------------------------
#pragma unroll
    for (int n = 0; n < 4; n++)
      h[n] = (f32x4&)*(const float4*)(biaspg + 64 + 16 * n + 4 * p);
#pragma unroll
    for (int n = 0; n < 4; n++) {
      bf16x8 a0 = *(const bf16x8*)&wl[(((4 + n) * 2 + 0) * 64 + lane) * 8];
      h[n] = __builtin_amdgcn_mfma_f32_16x16x32_bf16(a0, b0, h[n], 0, 0, 0);
      bf16x8 a1 = *(const bf16x8*)&wl[(((4 + n) * 2 + 1) * 64 + lane) * 8];
      h[n] = __builtin_amdgcn_mfma_f32_16x16x32_bf16(a1, b1, h[n], 0, 0, 0);
    }
#pragma unroll
    for (int n = 0; n < 4; n++) {
      f32x2 lo = sum3_fp8<false>(g1[n], g2[n], ga[n]);
      f32x2 hi = sum3_fp8<true >(g1[n], g2[n], ga[n]);
      h[n][0] += lo[0]; h[n][1] += lo[1]; h[n][2] += hi[0]; h[n][3] += hi[1];
    }
#pragma unroll
    for (int s2 = 0; s2 < 2; s2++) {
      union { unsigned u[4]; bf16x8 v; } t;
#pragma unroll
      for (int eh = 0; eh < 4; eh++) {
        const int e0 = 2 * eh;
        const int n = 2 * s2 + (e0 >> 2), j = e0 & 3;
        t.u[eh] = cvtpk_bf16(silu_(h[n][j]), silu_(h[n][j + 1]));
      }
      b2f[s2] = t.v;
    }
    f32x4 og[4];
#pragma unroll
    for (int n2 = 0; n2 < 4; n2++)
      og[n2] = (f32x4&)*(const float4*)(bg2 + 16 * n2 + 4 * p);
#pragma unroll
    for (int s2 = 0; s2 < 2; s2++) {
      const int ko = 32 * s2 + p8;
#pragma unroll
      for (int n2 = 0; n2 < 4; n2++) {
        bf16x8 a2 = *(const bf16x8*)(wg2t + (q + 16 * n2) * KH + ko);
        og[n2] = __builtin_amdgcn_mfma_f32_16x16x32_bf16(a2, b2f[s2], og[n2], 0, 0, 0);
      }
    }

    // epilogue: upd2[rank][d] = silu(oc)*sigm(og)*bw_fp8[bj][d]
    if (ok) {
      unsigned short* dst = upd2 + (long)rr * KD;
#pragma unroll
      for (int n2 = 0; n2 < 4; n2++) {
        f32x2 blo = __builtin_amdgcn_cvt_pk_f32_fp8((int)bw[n2], false);
        f32x2 bhi = __builtin_amdgcn_cvt_pk_f32_fp8((int)bw[n2], true);
        float f0 = sc[4 * n2 + 0] * sigm(og[n2][0]) * blo[0];
        float f1 = sc[4 * n2 + 1] * sigm(og[n2][1]) * blo[1];
        float f2 = sc[4 * n2 + 2] * sigm(og[n2][2]) * bhi[0];
        float f3 = sc[4 * n2 + 3] * sigm(og[n2][3]) * bhi[1];
        uint2 st;
        st.x = cvtpk_bf16(f0, f1);
        st.y = cvtpk_bf16(f2, f3);
        *(uint2*)(dst + 16 * n2 + 4 * p) = st;
      }
    }
    ci = nci; bi = nbi; bj = nbj;
  }
}

// ---- k_aggout: contiguous segment-sum(upd2)*bw[b] -> @Wo + bo + bond -> out ---
__global__ __launch_bounds__(256) void k_aggout(
    const float* __restrict__ bond, const float* __restrict__ bwt,
    const unsigned short* __restrict__ upd2,
    const int* __restrict__ off, const int* __restrict__ cnt,
    const unsigned short* __restrict__ wot, const float* __restrict__ bo,
    float* __restrict__ out, int na, int nb) {
  const int wave = threadIdx.x >> 6;
  const int lane = threadIdx.x & 63;
  const int r15 = lane & 15;
  const int ck = lane >> 4;
  const int base = blockIdx.x * 64 + wave * 16;
  const int b = base + r15;
  const bool hasseg = (b < na);
  const int bc = hasseg ? b : 0;
  const int o = off[bc];
  const int c = hasseg ? cnt[bc] : 0;
  const int d0 = ck * 8;

  float acc[16];
#pragma unroll
  for (int e = 0; e < 16; e++) acc[e] = 0.0f;

  int it = 0;
  for (; it + 2 <= c; it += 2) {
    const unsigned short* r0 = upd2 + (long)(o + it) * KD;
    const unsigned short* r1 = r0 + KD;
    bf16x8 l0 = *(const bf16x8*)(r0 + d0);
    bf16x8 h0 = *(const bf16x8*)(r0 + 32 + d0);
    bf16x8 l1 = *(const bf16x8*)(r1 + d0);
    bf16x8 h1 = *(const bf16x8*)(r1 + 32 + d0);
#pragma unroll
    for (int e = 0; e < 8; e++) {
      acc[e]     += bf2f((unsigned short)l0[e]) + bf2f((unsigned short)l1[e]);
      acc[8 + e] += bf2f((unsigned short)h0[e]) + bf2f((unsigned short)h1[e]);
    }
  }
  if (it < c) {
    const unsigned short* r0 = upd2 + (long)(o + it) * KD;
    bf16x8 l0 = *(const bf16x8*)(r0 + d0);
    bf16x8 h0 = *(const bf16x8*)(r0 + 32 + d0);
#pragma unroll
    for (int e = 0; e < 8; e++) {
      acc[e]     += bf2f((unsigned short)l0[e]);
      acc[8 + e] += bf2f((unsigned short)h0[e]);
    }
  }

  if (hasseg) {
    const float* w = bwt + (long)b * KD;
    float4 w0 = *(const float4*)(w + d0);
    float4 w1 = *(const float4*)(w + d0 + 4);
    float4 w2 = *(const float4*)(w + 32 + d0);
    float4 w3 = *(const float4*)(w + 32 + d0 + 4);
    acc[0] *= w0.x;  acc[1] *= w0.y;  acc[2] *= w0.z;  acc[3] *= w0.w;
    acc[4] *= w1.x;  acc[5] *= w1.y;  acc[6] *= w1.z;  acc[7] *= w1.w;
    acc[8] *= w2.x;  acc[9] *= w2.y;  acc[10] *= w2.z; acc[11] *= w2.w;
    acc[12] *= w3.x; acc[13] *= w3.y; acc[14] *= w3.z; acc[15] *= w3.w;
  }

  bf16x8 a[2];
  {
    union { unsigned u[4]; bf16x8 v; } t0, t1;
    t0.u[0] = cvtpk_bf16(acc[0], acc[1]);
    t0.u[1] = cvtpk_bf16(acc[2], acc[3]);
    t0.u[2] = cvtpk_bf16(acc[4], acc[5]);
    t0.u[3] = cvtpk_bf16(acc[6], acc[7]);
    t1.u[0] = cvtpk_bf16(acc[8], acc[9]);
    t1.u[1] = cvtpk_bf16(acc[10], acc[11]);
    t1.u[2] = cvtpk_bf16(acc[12], acc[13]);
    t1.u[3] = cvtpk_bf16(acc[14], acc[15]);
    a[0] = t0.v;
    a[1] = t1.v;
  }

  f32x4 acc2[4];
#pragma unroll
  for (int n = 0; n < 4; n++) {
    float bv = bo[n * 16 + r15];
    acc2[n] = (f32x4){bv, bv, bv, bv};
  }
#pragma unroll
  for (int s = 0; s < 2; s++) {
    const int koff = s * 32 + ck * 8;
#pragma unroll
    for (int n = 0; n < 4; n++) {
      bf16x8 bf = *(const bf16x8*)(wot + (n * 16 + r15) * KH + koff);
      acc2[n] = __builtin_amdgcn_mfma_f32_16x16x32_bf16(a[s], bf, acc2[n], 0, 0, 0);
    }
  }
#pragma unroll
  for (int n = 0; n < 4; n++) {
#pragma unroll
    for (int j = 0; j < 4; j++) {
      const int orow = base + ck * 4 + j;
      if (orow < nb) {
        const int d = n * 16 + r15;
        out[(long)orow * KD + d] = acc2[n][j] + bond[(long)orow * KD + d];
      }
    }
  }
}

extern "C" void kernel_launch(void* const* d_in, const int* in_sizes, int n_in,
                              void* d_out, int out_size, void* d_ws, size_t ws_size,
                              hipStream_t stream) {
  const float* atom = (const float*)d_in[0];
  const float* bond = (const float*)d_in[1];
  const float* bwt  = (const float*)d_in[2];
  const float* ang  = (const float*)d_in[3];
  const int*   bgr  = (const int*)d_in[4];
  const float* wc1 = (const float*)d_in[5];
  const float* bc1 = (const float*)d_in[6];
  const float* wc2 = (const float*)d_in[7];
  const float* bc2 = (const float*)d_in[8];
  const float* wg1 = (const float*)d_in[9];
  const float* bg1 = (const float*)d_in[10];
  const float* wg2 = (const float*)d_in[11];
  const float* bg2 = (const float*)d_in[12];
  const float* wo  = (const float*)d_in[13];
  const float* bo  = (const float*)d_in[14];

  const int na = in_sizes[0] / KD;   // atoms (40000); all bond_graph indices < na
  const int nb = in_sizes[1] / KD;   // bonds (200000)
  const int ng = in_sizes[4] / 3;    // angles (500000)
  float* out = (float*)d_out;

  char* pp = (char*)d_ws;
  auto alloc = [&](size_t bytes) { char* r = pp; pp += (bytes + 255) & ~(size_t)255; return r; };
  unsigned short* wpb  = (unsigned short*)alloc(16384 * 2);
  unsigned short* wpa  = (unsigned short*)alloc(8192 * 2);
  unsigned short* wpg  = (unsigned short*)alloc(8192 * 2);
  unsigned short* wc2t = (unsigned short*)alloc((size_t)KH * KD * 2);
  unsigned short* wg2t = (unsigned short*)alloc((size_t)KH * KD * 2);
  unsigned short* wot  = (unsigned short*)alloc((size_t)KH * KD * 2);
  float* biaspg        = (float*)alloc(128 * 4);
  unsigned char* PBX   = (unsigned char*)alloc((size_t)na * 384);       // 15.4 MB
  unsigned char* PA    = (unsigned char*)alloc((size_t)na * 128);       // 5.1 MB
  unsigned short* upd2 = (unsigned short*)alloc((size_t)ng * KD * 2);   // 64 MB
  int* cnt  = (int*)alloc((size_t)na * 4);
  int* cur  = (int*)alloc((size_t)na * 4);
  int* offb = (int*)alloc((size_t)na * 4);
  int* part = (int*)alloc((size_t)na * 4);
  int* bsum  = (int*)alloc(4096);
  int* bscan = (int*)alloc(4096);

  const int nblk = (na + 255) / 256;   // 157 <= 1024

  hipMemsetAsync(cnt, 0, (size_t)na * 4, stream);

  k_prep<<<(ng + 255) / 256, 256, 0, stream>>>(wc1, wg1, wc2, wg2, wo, bc1, bg1,
                                               wpb, wpa, wpg, wc2t, wg2t, wot, biaspg,
                                               bgr, cnt, ng);
  k_scan1<<<nblk, 256, 0, stream>>>(cnt, part, bsum, na);
  k_scan2<<<1, 1024, 0, stream>>>(bsum, bscan, nblk);
  k_scan3<<<nblk, 256, 0, stream>>>(part, bscan, offb, cur, na);

  const int tb = (na + 63) / 64;       // 625
  k_partial<256><<<tb, 256, 0, stream>>>(bond, wpb, PBX, na, 384, bwt);
  k_partial<128><<<tb, 256, 0, stream>>>(atom, wpa, PA, na, 128, (const float*)nullptr);

  k_fused<<<4096, 256, 0, stream>>>(ang, wpg, biaspg, bgr, offb, cur,
                                    PBX, PA, wc2t, wg2t, bc2, bg2, upd2, ng);

  k_aggout<<<(nb + 63) / 64, 256, 0, stream>>>(bond, bwt, upd2, offb, cnt,
                                               wot, bo, out, na, nb);
}